// Round 1
// baseline (966.157 us; speedup 1.0000x reference)
//
#include <hip/hip_runtime.h>
#include <hip/hip_bf16.h>

// DiT block: B=8, S=1024, D=1152, H=16, HD=72, HID=4608
// All big GEMMs in bf16 MFMA (16x16x32), f32 accumulate.
// Weights pre-transposed to [N,K] bf16 so B-fragments are contiguous ds_read_b128.

typedef unsigned short u16;
typedef __attribute__((ext_vector_type(8))) short bf16x8;
typedef __attribute__((ext_vector_type(4))) float f32x4;

#define MFMA16(a, b, c) __builtin_amdgcn_mfma_f32_16x16x32_bf16((a), (b), (c), 0, 0, 0)

__device__ __forceinline__ u16 f2bf(float f) {
  __hip_bfloat16 h = __float2bfloat16(f);
  return __builtin_bit_cast(u16, h);
}

// ---------------- silu(c) ----------------
__global__ void k_silu(const float* __restrict__ c, float* __restrict__ o, int n) {
  int i = blockIdx.x * 256 + threadIdx.x;
  if (i < n) { float v = c[i]; o[i] = v / (1.f + __expf(-v)); }
}

// ------- mod = silu_c[8,1152] @ ada_w[1152,6912] + ada_b  (tiny GEMM, fp32 vector) -------
__global__ __launch_bounds__(256) void k_modproj(const float* __restrict__ sc,
                                                 const float* __restrict__ aw,
                                                 const float* __restrict__ ab,
                                                 float* __restrict__ mo) {
  __shared__ float lc[8][1152];
  for (int i = threadIdx.x; i < 9216; i += 256) ((float*)lc)[i] = sc[i];
  __syncthreads();
  int j = blockIdx.x * 256 + threadIdx.x;  // 27 blocks * 256 = 6912
  float acc[8] = {0, 0, 0, 0, 0, 0, 0, 0};
  for (int k = 0; k < 1152; ++k) {
    float w = aw[(size_t)k * 6912 + j];
    #pragma unroll
    for (int b = 0; b < 8; ++b) acc[b] += lc[b][k] * w;
  }
  float bias = ab[j];
  #pragma unroll
  for (int b = 0; b < 8; ++b) mo[(size_t)b * 6912 + j] = acc[b] + bias;
}

// ------- transpose-convert: in[K][N] f32 -> out[N][K] bf16 (tiled, coalesced both sides) -------
__global__ __launch_bounds__(256) void k_tcvt(const float* __restrict__ in, u16* __restrict__ out,
                                              int K, int N) {
  __shared__ float t[32][33];
  int tx = threadIdx.x & 31, ty = threadIdx.x >> 5;  // 32x8
  size_t bx = (size_t)blockIdx.x * 32, by = (size_t)blockIdx.y * 32;
  #pragma unroll
  for (int i = 0; i < 4; ++i) t[ty + 8 * i][tx] = in[(by + ty + 8 * i) * N + bx + tx];
  __syncthreads();
  #pragma unroll
  for (int i = 0; i < 4; ++i) out[(bx + ty + 8 * i) * K + by + tx] = f2bf(t[tx][ty + 8 * i]);
}

// ------- fused LayerNorm + modulate -> bf16 row (one block per row) -------
__global__ __launch_bounds__(256) void k_lnmod(const float* __restrict__ xin,
                                               const float* __restrict__ w,
                                               const float* __restrict__ bs,
                                               const float* __restrict__ mo,
                                               int sh_off, int sc_off, u16* __restrict__ o) {
  int row = blockIdx.x;
  int b = row >> 10;
  int tid = threadIdx.x;
  const float4* x4 = (const float4*)(xin + (size_t)row * 1152);
  float4 v0 = x4[tid];
  float4 v1 = make_float4(0.f, 0.f, 0.f, 0.f);
  if (tid < 32) v1 = x4[256 + tid];
  float s = v0.x + v0.y + v0.z + v0.w + v1.x + v1.y + v1.z + v1.w;
  float sq = v0.x * v0.x + v0.y * v0.y + v0.z * v0.z + v0.w * v0.w +
             v1.x * v1.x + v1.y * v1.y + v1.z * v1.z + v1.w * v1.w;
  #pragma unroll
  for (int d = 32; d > 0; d >>= 1) { s += __shfl_down(s, d); sq += __shfl_down(sq, d); }
  __shared__ float ps[4], pq[4];
  int wid = tid >> 6, lane = tid & 63;
  if (lane == 0) { ps[wid] = s; pq[wid] = sq; }
  __syncthreads();
  float S = ps[0] + ps[1] + ps[2] + ps[3];
  float SQ = pq[0] + pq[1] + pq[2] + pq[3];
  float mean = S * (1.f / 1152.f);
  float var = SQ * (1.f / 1152.f) - mean * mean;
  float rs = rsqrtf(var + 1e-5f);
  const float* shp = mo + (size_t)b * 6912 + sh_off;
  const float* scp = mo + (size_t)b * 6912 + sc_off;
  u16* orow = o + (size_t)row * 1152;
  {
    int col = 4 * tid;
    ushort4 u; float y;
    y = (v0.x - mean) * rs * w[col + 0] + bs[col + 0]; u.x = f2bf(y * (1.f + scp[col + 0]) + shp[col + 0]);
    y = (v0.y - mean) * rs * w[col + 1] + bs[col + 1]; u.y = f2bf(y * (1.f + scp[col + 1]) + shp[col + 1]);
    y = (v0.z - mean) * rs * w[col + 2] + bs[col + 2]; u.z = f2bf(y * (1.f + scp[col + 2]) + shp[col + 2]);
    y = (v0.w - mean) * rs * w[col + 3] + bs[col + 3]; u.w = f2bf(y * (1.f + scp[col + 3]) + shp[col + 3]);
    *(ushort4*)&orow[col] = u;
  }
  if (tid < 32) {
    int col = 1024 + 4 * tid;
    ushort4 u; float y;
    y = (v1.x - mean) * rs * w[col + 0] + bs[col + 0]; u.x = f2bf(y * (1.f + scp[col + 0]) + shp[col + 0]);
    y = (v1.y - mean) * rs * w[col + 1] + bs[col + 1]; u.y = f2bf(y * (1.f + scp[col + 1]) + shp[col + 1]);
    y = (v1.z - mean) * rs * w[col + 2] + bs[col + 2]; u.z = f2bf(y * (1.f + scp[col + 2]) + shp[col + 2]);
    y = (v1.w - mean) * rs * w[col + 3] + bs[col + 3]; u.w = f2bf(y * (1.f + scp[col + 3]) + shp[col + 3]);
    *(ushort4*)&orow[col] = u;
  }
}

// ------- bf16 MFMA GEMM: C[M,N] = A[M,K] @ Bt[N,K]^T, 128x128 tile, 4 waves, BK=32 -------
// EPI 0: Cb = bf16(acc)                       (q/k/v)
// EPI 1: Cf = res + mod[b,goff+col]*(acc+bias) (wo-proj -> x1, fc2 -> out)
// EPI 2: Cb = bf16(gelu(acc+bias))            (fc1 -> m1)
template <int EPI>
__global__ __launch_bounds__(256) void k_gemm(const u16* __restrict__ A, const u16* __restrict__ Bt,
                                              int K, u16* __restrict__ Cb, float* __restrict__ Cf,
                                              const float* __restrict__ bias,
                                              const float* __restrict__ res,
                                              const float* __restrict__ mo, int goff) {
  const int tid = threadIdx.x;
  const int wid = tid >> 6, lane = tid & 63;
  const int wr = wid >> 1, wc = wid & 1;
  const int lr = lane & 15, kg = lane >> 4;
  const int tM = blockIdx.y * 128, tN = blockIdx.x * 128;
  const int N = gridDim.x * 128;
  __shared__ u16 lA[128][40];  // +8 pad: row stride 80B -> 2-way bank alias (free)
  __shared__ u16 lB[128][40];
  f32x4 acc[4][4];
  #pragma unroll
  for (int m = 0; m < 4; ++m)
    #pragma unroll
    for (int n = 0; n < 4; ++n) acc[m][n] = f32x4{0.f, 0.f, 0.f, 0.f};

  const int row0 = tid >> 2, seg = tid & 3;
  const u16* Ap = A + (size_t)(tM + row0) * K + seg * 8;
  const u16* Bp = Bt + (size_t)(tN + row0) * K + seg * 8;

  for (int ks = 0; ks < K; ks += 32) {
    __syncthreads();
    *(uint4*)&lA[row0][seg * 8]      = *(const uint4*)(Ap + ks);
    *(uint4*)&lA[row0 + 64][seg * 8] = *(const uint4*)(Ap + (size_t)64 * K + ks);
    *(uint4*)&lB[row0][seg * 8]      = *(const uint4*)(Bp + ks);
    *(uint4*)&lB[row0 + 64][seg * 8] = *(const uint4*)(Bp + (size_t)64 * K + ks);
    __syncthreads();
    bf16x8 af[4], bfr[4];
    #pragma unroll
    for (int m = 0; m < 4; ++m) af[m] = *(const bf16x8*)&lA[wr * 64 + m * 16 + lr][kg * 8];
    #pragma unroll
    for (int n = 0; n < 4; ++n) bfr[n] = *(const bf16x8*)&lB[wc * 64 + n * 16 + lr][kg * 8];
    #pragma unroll
    for (int m = 0; m < 4; ++m)
      #pragma unroll
      for (int n = 0; n < 4; ++n) acc[m][n] = MFMA16(af[m], bfr[n], acc[m][n]);
  }
  // epilogue: D row=(lane>>4)*4+reg, col=lane&15 (m89-verified)
  #pragma unroll
  for (int m = 0; m < 4; ++m)
    #pragma unroll
    for (int n = 0; n < 4; ++n)
      #pragma unroll
      for (int r = 0; r < 4; ++r) {
        int grow = tM + wr * 64 + m * 16 + kg * 4 + r;
        int gcol = tN + wc * 64 + n * 16 + lr;
        size_t idx = (size_t)grow * N + gcol;
        float v = acc[m][n][r];
        if (EPI == 0) {
          Cb[idx] = f2bf(v);
        } else if (EPI == 1) {
          float g = mo[(size_t)(grow >> 10) * 6912 + goff + gcol];
          Cf[idx] = res[idx] + g * (v + bias[gcol]);
        } else {
          float z = v + bias[gcol];
          Cb[idx] = f2bf(0.5f * z * (1.f + erff(z * 0.70710678118f)));
        }
      }
}

// ------- flash attention: 1 block = (b, h, 64-row Q tile); KV tiles of 64; d padded 72->96 -------
__global__ __launch_bounds__(256) void k_attn(const u16* __restrict__ Q, const u16* __restrict__ Kb,
                                              const u16* __restrict__ Vb, u16* __restrict__ O) {
  const int tid = threadIdx.x;
  const int w = tid >> 6, lane = tid & 63;
  const int lr = lane & 15, kg = lane >> 4;
  const int bx = blockIdx.x;
  const int qt = bx & 15, h = (bx >> 4) & 15, b = bx >> 8;

  __shared__ u16 lQ[64][104];   // [qrow][d], d zero-padded 72..95
  __shared__ u16 lK[64][104];   // [krow][d], d zero-padded 72..95
  __shared__ u16 lVt[80][72];   // [d][kv] transposed; rows 72..79 zeroed
  __shared__ u16 lP[4][16][72]; // wave-private P [qrow][kv]

  const size_t base = (size_t)b * 1024 * 1152 + h * 72;

  for (int L = tid; L < 576; L += 256) {
    int r = L / 9, s = L % 9;
    *(uint4*)&lQ[r][s * 8] = *(const uint4*)(Q + base + (size_t)(qt * 64 + r) * 1152 + s * 8);
  }
  for (int L = tid; L < 192; L += 256) {
    int r = L / 3, s = L % 3;
    *(uint4*)&lQ[r][72 + s * 8] = make_uint4(0, 0, 0, 0);
  }
  for (int L = tid; L < 512; L += 256) lVt[72 + (L >> 6)][L & 63] = 0;
  __syncthreads();

  bf16x8 aq[3];
  #pragma unroll
  for (int ks = 0; ks < 3; ++ks) aq[ks] = *(const bf16x8*)&lQ[w * 16 + lr][ks * 32 + kg * 8];

  float mrun[4], lrun[4];
  f32x4 oacc[5];
  #pragma unroll
  for (int r = 0; r < 4; ++r) { mrun[r] = -1e30f; lrun[r] = 0.f; }
  #pragma unroll
  for (int nd = 0; nd < 5; ++nd) oacc[nd] = f32x4{0.f, 0.f, 0.f, 0.f};

  for (int kt = 0; kt < 16; ++kt) {
    __syncthreads();  // previous tile's lK/lVt reads done
    for (int L = tid; L < 576; L += 256) {
      int r = L / 9, s = L % 9;
      *(uint4*)&lK[r][s * 8] = *(const uint4*)(Kb + base + (size_t)(kt * 64 + r) * 1152 + s * 8);
    }
    for (int L = tid; L < 192; L += 256) {
      int r = L / 3, s = L % 3;
      *(uint4*)&lK[r][72 + s * 8] = make_uint4(0, 0, 0, 0);
    }
    for (int L = tid; L < 576; L += 256) {
      int r = L / 9, s = L % 9;  // kv row r, d segment s
      uint4 raw = *(const uint4*)(Vb + base + (size_t)(kt * 64 + r) * 1152 + s * 8);
      const u16* e = (const u16*)&raw;
      #pragma unroll
      for (int j = 0; j < 8; ++j) lVt[s * 8 + j][r] = e[j];
    }
    __syncthreads();

    // S = Q @ K^T  (wave owns 16 q-rows x 64 keys)
    f32x4 sfr[4];
    #pragma unroll
    for (int kb = 0; kb < 4; ++kb) {
      f32x4 sv = f32x4{0.f, 0.f, 0.f, 0.f};
      #pragma unroll
      for (int ks = 0; ks < 3; ++ks) {
        bf16x8 bk = *(const bf16x8*)&lK[kb * 16 + lr][ks * 32 + kg * 8];
        sv = MFMA16(aq[ks], bk, sv);
      }
      sfr[kb] = sv;
    }
    const float scale = 0.11785113019775793f;  // 1/sqrt(72)
    #pragma unroll
    for (int kb = 0; kb < 4; ++kb)
      #pragma unroll
      for (int r = 0; r < 4; ++r) sfr[kb][r] *= scale;

    // online softmax: row = kg*4+r, 64 cols spread over 16 lanes x 4 regs
    float pm[4], al[4];
    #pragma unroll
    for (int r = 0; r < 4; ++r) {
      float x = fmaxf(fmaxf(sfr[0][r], sfr[1][r]), fmaxf(sfr[2][r], sfr[3][r]));
      #pragma unroll
      for (int m = 1; m < 16; m <<= 1) x = fmaxf(x, __shfl_xor(x, m, 16));
      float mn = fmaxf(mrun[r], x);
      al[r] = __expf(mrun[r] - mn);
      mrun[r] = mn;
      pm[r] = mn;
    }
    float rsum[4] = {0.f, 0.f, 0.f, 0.f};
    #pragma unroll
    for (int kb = 0; kb < 4; ++kb)
      #pragma unroll
      for (int r = 0; r < 4; ++r) {
        float p = __expf(sfr[kb][r] - pm[r]);
        rsum[r] += p;
        lP[w][kg * 4 + r][kb * 16 + lr] = f2bf(p);
      }
    #pragma unroll
    for (int r = 0; r < 4; ++r) {
      float t = rsum[r];
      #pragma unroll
      for (int m = 1; m < 16; m <<= 1) t += __shfl_xor(t, m, 16);
      lrun[r] = lrun[r] * al[r] + t;
    }
    #pragma unroll
    for (int nd = 0; nd < 5; ++nd)
      #pragma unroll
      for (int r = 0; r < 4; ++r) oacc[nd][r] *= al[r];

    // O += P @ V
    #pragma unroll
    for (int kstep = 0; kstep < 2; ++kstep) {
      bf16x8 pa = *(const bf16x8*)&lP[w][lr][kstep * 32 + kg * 8];
      #pragma unroll
      for (int nd = 0; nd < 5; ++nd) {
        bf16x8 bv = *(const bf16x8*)&lVt[nd * 16 + lr][kstep * 32 + kg * 8];
        oacc[nd] = MFMA16(pa, bv, oacc[nd]);
      }
    }
  }

  #pragma unroll
  for (int nd = 0; nd < 5; ++nd)
    #pragma unroll
    for (int r = 0; r < 4; ++r) {
      int d = nd * 16 + lr;
      if (d < 72) {
        size_t row = (size_t)b * 1024 + qt * 64 + w * 16 + kg * 4 + r;
        O[row * 1152 + h * 72 + d] = f2bf(oacc[nd][r] / lrun[r]);
      }
    }
}

extern "C" void kernel_launch(void* const* d_in, const int* in_sizes, int n_in,
                              void* d_out, int out_size, void* d_ws, size_t ws_size,
                              hipStream_t stream) {
  const float* x     = (const float*)d_in[0];
  const float* c     = (const float*)d_in[1];
  const float* ln1_w = (const float*)d_in[2];
  const float* ln1_b = (const float*)d_in[3];
  const float* wq    = (const float*)d_in[4];
  const float* wk    = (const float*)d_in[5];
  const float* wv    = (const float*)d_in[6];
  const float* wo    = (const float*)d_in[7];
  const float* wo_b  = (const float*)d_in[8];
  const float* ln2_w = (const float*)d_in[9];
  const float* ln2_b = (const float*)d_in[10];
  const float* fc1_w = (const float*)d_in[11];
  const float* fc1_b = (const float*)d_in[12];
  const float* fc2_w = (const float*)d_in[13];
  const float* fc2_b = (const float*)d_in[14];
  const float* ada_w = (const float*)d_in[15];
  const float* ada_b = (const float*)d_in[16];
  float* out = (float*)d_out;

  char* base = (char*)d_ws;
  size_t off = 0;
  auto alloc = [&](size_t nbytes) -> void* {
    void* p = base + off;
    off += (nbytes + 255) & ~(size_t)255;
    return p;
  };
  const size_t MD = 8192ull * 1152;  // rows x D
  float* silu_c = (float*)alloc(9216 * 4);
  float* modb   = (float*)alloc(55296 * 4);
  u16* wqT  = (u16*)alloc(1152ull * 1152 * 2);
  u16* wkT  = (u16*)alloc(1152ull * 1152 * 2);
  u16* wvT  = (u16*)alloc(1152ull * 1152 * 2);
  u16* woT  = (u16*)alloc(1152ull * 1152 * 2);
  u16* fc1T = (u16*)alloc(4608ull * 1152 * 2);
  u16* fc2T = (u16*)alloc(1152ull * 4608 * 2);
  u16* hbuf = (u16*)alloc(MD * 2);            // h -> attnO -> h2
  float* x1 = (float*)alloc(MD * 4);
  u16* big  = (u16*)alloc(8192ull * 4608 * 2); // q,k,v then m1
  u16* qb = big, *kb = big + MD, *vb = big + 2 * MD;
  u16* m1 = big;

  k_silu<<<36, 256, 0, stream>>>(c, silu_c, 9216);
  k_modproj<<<27, 256, 0, stream>>>(silu_c, ada_w, ada_b, modb);
  k_tcvt<<<dim3(36, 36), 256, 0, stream>>>(wq, wqT, 1152, 1152);
  k_tcvt<<<dim3(36, 36), 256, 0, stream>>>(wk, wkT, 1152, 1152);
  k_tcvt<<<dim3(36, 36), 256, 0, stream>>>(wv, wvT, 1152, 1152);
  k_tcvt<<<dim3(36, 36), 256, 0, stream>>>(wo, woT, 1152, 1152);
  k_tcvt<<<dim3(144, 36), 256, 0, stream>>>(fc1_w, fc1T, 1152, 4608);
  k_tcvt<<<dim3(36, 144), 256, 0, stream>>>(fc2_w, fc2T, 4608, 1152);

  // h = modulate(LN(x), sh_msa, sc_msa)
  k_lnmod<<<8192, 256, 0, stream>>>(x, ln1_w, ln1_b, modb, 0, 1152, hbuf);
  // q,k,v
  k_gemm<0><<<dim3(9, 64), 256, 0, stream>>>(hbuf, wqT, 1152, qb, nullptr, nullptr, nullptr, nullptr, 0);
  k_gemm<0><<<dim3(9, 64), 256, 0, stream>>>(hbuf, wkT, 1152, kb, nullptr, nullptr, nullptr, nullptr, 0);
  k_gemm<0><<<dim3(9, 64), 256, 0, stream>>>(hbuf, wvT, 1152, vb, nullptr, nullptr, nullptr, nullptr, 0);
  // attention -> O (reuse hbuf)
  k_attn<<<2048, 256, 0, stream>>>(qb, kb, vb, hbuf);
  // x1 = x + g_msa*(O@wo + wo_b)
  k_gemm<1><<<dim3(9, 64), 256, 0, stream>>>(hbuf, woT, 1152, nullptr, x1, wo_b, x, modb, 2304);
  // h2 = modulate(LN(x1), sh_mlp, sc_mlp)
  k_lnmod<<<8192, 256, 0, stream>>>(x1, ln2_w, ln2_b, modb, 3456, 4608, hbuf);
  // m1 = gelu(h2@fc1 + fc1_b)
  k_gemm<2><<<dim3(36, 64), 256, 0, stream>>>(hbuf, fc1T, 1152, m1, nullptr, fc1_b, nullptr, nullptr, 0);
  // out = x1 + g_mlp*(m1@fc2 + fc2_b)
  k_gemm<1><<<dim3(9, 64), 256, 0, stream>>>(m1, fc2T, 4608, nullptr, out, fc2_b, x1, modb, 5760);
}

// Round 2
// 825.710 us; speedup vs baseline: 1.1701x; 1.1701x over previous
//
#include <hip/hip_runtime.h>
#include <hip/hip_bf16.h>

// DiT block: B=8, S=1024, D=1152, H=16, HD=72, HID=4608
// GEMMs: bf16 MFMA 16x16x32, f32 accum, 128x128 tile, BK=32,
// global_load_lds width-16 staging (m97 structure), XCD-swizzled grid.

typedef unsigned short u16;
typedef __attribute__((ext_vector_type(8))) short bf16x8;
typedef __attribute__((ext_vector_type(4))) float f32x4;

#define MFMA16(a, b, c) __builtin_amdgcn_mfma_f32_16x16x32_bf16((a), (b), (c), 0, 0, 0)

__device__ __forceinline__ u16 f2bf(float f) {
  __hip_bfloat16 h = __float2bfloat16(f);
  return __builtin_bit_cast(u16, h);
}

__device__ __forceinline__ void gload16(const u16* g, u16* l) {
  __builtin_amdgcn_global_load_lds(
      (const __attribute__((address_space(1))) unsigned int*)(const void*)g,
      (__attribute__((address_space(3))) unsigned int*)(void*)l, 16, 0, 0);
}

// ---------------- silu(c) ----------------
__global__ void k_silu(const float* __restrict__ c, float* __restrict__ o, int n) {
  int i = blockIdx.x * 256 + threadIdx.x;
  if (i < n) { float v = c[i]; o[i] = v / (1.f + __expf(-v)); }
}

// ------- mod projection, split-K stage 1: partial[kc][8][6912] -------
__global__ __launch_bounds__(256) void k_modproj1(const float* __restrict__ sc,
                                                  const float* __restrict__ aw,
                                                  float* __restrict__ partial) {
  __shared__ float lc[8][144];
  int kc = blockIdx.y;
  for (int i = threadIdx.x; i < 1152; i += 256) {
    int b = i / 144, k = i % 144;
    lc[b][k] = sc[b * 1152 + kc * 144 + k];
  }
  __syncthreads();
  int j = blockIdx.x * 256 + threadIdx.x;
  float acc[8] = {0, 0, 0, 0, 0, 0, 0, 0};
  for (int k = 0; k < 144; ++k) {
    float w = aw[(size_t)(kc * 144 + k) * 6912 + j];
    #pragma unroll
    for (int b = 0; b < 8; ++b) acc[b] += lc[b][k] * w;
  }
  #pragma unroll
  for (int b = 0; b < 8; ++b) partial[((size_t)kc * 8 + b) * 6912 + j] = acc[b];
}

// ------- mod projection stage 2: reduce 8 partials + bias -------
__global__ __launch_bounds__(256) void k_modproj2(const float* __restrict__ partial,
                                                  const float* __restrict__ ab,
                                                  float* __restrict__ mo) {
  int j = blockIdx.x * 256 + threadIdx.x;
  float bias = ab[j];
  #pragma unroll
  for (int b = 0; b < 8; ++b) {
    float s = 0.f;
    #pragma unroll
    for (int kc = 0; kc < 8; ++kc) s += partial[((size_t)kc * 8 + b) * 6912 + j];
    mo[(size_t)b * 6912 + j] = s + bias;
  }
}

// ------- transpose-convert: in[K][N] f32 -> out[N][K] bf16 -------
__global__ __launch_bounds__(256) void k_tcvt(const float* __restrict__ in, u16* __restrict__ out,
                                              int K, int N) {
  __shared__ float t[32][33];
  int tx = threadIdx.x & 31, ty = threadIdx.x >> 5;  // 32x8
  size_t bx = (size_t)blockIdx.x * 32, by = (size_t)blockIdx.y * 32;
  #pragma unroll
  for (int i = 0; i < 4; ++i) t[ty + 8 * i][tx] = in[(by + ty + 8 * i) * N + bx + tx];
  __syncthreads();
  #pragma unroll
  for (int i = 0; i < 4; ++i) out[(bx + ty + 8 * i) * K + by + tx] = f2bf(t[tx][ty + 8 * i]);
}

// ------- fused LayerNorm + modulate -> bf16 row (one block per row) -------
__global__ __launch_bounds__(256) void k_lnmod(const float* __restrict__ xin,
                                               const float* __restrict__ w,
                                               const float* __restrict__ bs,
                                               const float* __restrict__ mo,
                                               int sh_off, int sc_off, u16* __restrict__ o) {
  int row = blockIdx.x;
  int b = row >> 10;
  int tid = threadIdx.x;
  const float4* x4 = (const float4*)(xin + (size_t)row * 1152);
  float4 v0 = x4[tid];
  float4 v1 = make_float4(0.f, 0.f, 0.f, 0.f);
  if (tid < 32) v1 = x4[256 + tid];
  float s = v0.x + v0.y + v0.z + v0.w + v1.x + v1.y + v1.z + v1.w;
  float sq = v0.x * v0.x + v0.y * v0.y + v0.z * v0.z + v0.w * v0.w +
             v1.x * v1.x + v1.y * v1.y + v1.z * v1.z + v1.w * v1.w;
  #pragma unroll
  for (int d = 32; d > 0; d >>= 1) { s += __shfl_down(s, d); sq += __shfl_down(sq, d); }
  __shared__ float ps[4], pq[4];
  int wid = tid >> 6, lane = tid & 63;
  if (lane == 0) { ps[wid] = s; pq[wid] = sq; }
  __syncthreads();
  float S = ps[0] + ps[1] + ps[2] + ps[3];
  float SQ = pq[0] + pq[1] + pq[2] + pq[3];
  float mean = S * (1.f / 1152.f);
  float var = SQ * (1.f / 1152.f) - mean * mean;
  float rs = rsqrtf(var + 1e-5f);
  const float* shp = mo + (size_t)b * 6912 + sh_off;
  const float* scp = mo + (size_t)b * 6912 + sc_off;
  u16* orow = o + (size_t)row * 1152;
  {
    int col = 4 * tid;
    ushort4 u; float y;
    y = (v0.x - mean) * rs * w[col + 0] + bs[col + 0]; u.x = f2bf(y * (1.f + scp[col + 0]) + shp[col + 0]);
    y = (v0.y - mean) * rs * w[col + 1] + bs[col + 1]; u.y = f2bf(y * (1.f + scp[col + 1]) + shp[col + 1]);
    y = (v0.z - mean) * rs * w[col + 2] + bs[col + 2]; u.z = f2bf(y * (1.f + scp[col + 2]) + shp[col + 2]);
    y = (v0.w - mean) * rs * w[col + 3] + bs[col + 3]; u.w = f2bf(y * (1.f + scp[col + 3]) + shp[col + 3]);
    *(ushort4*)&orow[col] = u;
  }
  if (tid < 32) {
    int col = 1024 + 4 * tid;
    ushort4 u; float y;
    y = (v1.x - mean) * rs * w[col + 0] + bs[col + 0]; u.x = f2bf(y * (1.f + scp[col + 0]) + shp[col + 0]);
    y = (v1.y - mean) * rs * w[col + 1] + bs[col + 1]; u.y = f2bf(y * (1.f + scp[col + 1]) + shp[col + 1]);
    y = (v1.z - mean) * rs * w[col + 2] + bs[col + 2]; u.z = f2bf(y * (1.f + scp[col + 2]) + shp[col + 2]);
    y = (v1.w - mean) * rs * w[col + 3] + bs[col + 3]; u.w = f2bf(y * (1.f + scp[col + 3]) + shp[col + 3]);
    *(ushort4*)&orow[col] = u;
  }
}

// ------- bf16 MFMA GEMM, m97 structure: C[M,N] = A[M,K] @ Bt[N,K]^T -------
// 128x128 tile, BK=32, linear LDS, global_load_lds w=16, XCD swizzle.
// EPI 0: Cb = bf16(acc); EPI 1: Cf = res + mod*(acc+bias); EPI 2: Cb = bf16(gelu(acc+bias))
template <int EPI>
__global__ __launch_bounds__(256) void k_gemm(const u16* __restrict__ A, const u16* __restrict__ Bt,
                                              int K, u16* __restrict__ Cb, float* __restrict__ Cf,
                                              const float* __restrict__ bias,
                                              const float* __restrict__ res,
                                              const float* __restrict__ mo, int goff) {
  const int tid = threadIdx.x;
  const int w = tid >> 6, lane = tid & 63;
  const int wr = w >> 1, wc = w & 1;
  const int lr = lane & 15, kg = lane >> 4;

  // XCD-aware bijective swizzle (all grids have nwg % 8 == 0)
  const int nwg = gridDim.x * gridDim.y;
  const int id = blockIdx.y * gridDim.x + blockIdx.x;
  const int swz = (id & 7) * (nwg >> 3) + (id >> 3);
  const int tM = (swz / gridDim.x) * 128, tN = (swz % gridDim.x) * 128;
  const int N = gridDim.x * 128;

  __shared__ u16 lA[128 * 32];
  __shared__ u16 lB[128 * 32];
  f32x4 acc[4][4];
  #pragma unroll
  for (int m = 0; m < 4; ++m)
    #pragma unroll
    for (int n = 0; n < 4; ++n) acc[m][n] = f32x4{0.f, 0.f, 0.f, 0.f};

  // staging: wave w covers rows [w*32, w*32+32) of each tile, 2 chunks of 16 rows.
  // lane l -> row chunkbase + l/4, bytes (l&3)*16 (matches HW dest base + l*16).
  const int lrow = lane >> 2, lseg = lane & 3;
  const u16* gA = A + (size_t)(tM + w * 32 + lrow) * K + lseg * 8;
  const u16* gB = Bt + (size_t)(tN + w * 32 + lrow) * K + lseg * 8;
  u16* lA0 = lA + (w * 32) * 32;
  u16* lA1 = lA + (w * 32 + 16) * 32;
  u16* lB0 = lB + (w * 32) * 32;
  u16* lB1 = lB + (w * 32 + 16) * 32;
  const size_t rstep = (size_t)16 * K;

  for (int ks = 0; ks < K; ks += 32) {
    __syncthreads();
    gload16(gA + ks, lA0);
    gload16(gA + rstep + ks, lA1);
    gload16(gB + ks, lB0);
    gload16(gB + rstep + ks, lB1);
    __syncthreads();
    bf16x8 af[4], bfr[4];
    #pragma unroll
    for (int m = 0; m < 4; ++m) af[m] = *(const bf16x8*)&lA[(wr * 64 + m * 16 + lr) * 32 + kg * 8];
    #pragma unroll
    for (int n = 0; n < 4; ++n) bfr[n] = *(const bf16x8*)&lB[(wc * 64 + n * 16 + lr) * 32 + kg * 8];
    #pragma unroll
    for (int m = 0; m < 4; ++m)
      #pragma unroll
      for (int n = 0; n < 4; ++n) acc[m][n] = MFMA16(af[m], bfr[n], acc[m][n]);
  }
  // epilogue: D row=(lane>>4)*4+reg, col=lane&15
  #pragma unroll
  for (int m = 0; m < 4; ++m)
    #pragma unroll
    for (int n = 0; n < 4; ++n)
      #pragma unroll
      for (int r = 0; r < 4; ++r) {
        int grow = tM + wr * 64 + m * 16 + kg * 4 + r;
        int gcol = tN + wc * 64 + n * 16 + lr;
        size_t idx = (size_t)grow * N + gcol;
        float v = acc[m][n][r];
        if (EPI == 0) {
          Cb[idx] = f2bf(v);
        } else if (EPI == 1) {
          float g = mo[(size_t)(grow >> 10) * 6912 + goff + gcol];
          Cf[idx] = res[idx] + g * (v + bias[gcol]);
        } else {
          float z = v + bias[gcol];
          Cb[idx] = f2bf(0.5f * z * (1.f + erff(z * 0.70710678118f)));
        }
      }
}

// ------- flash attention over fused QKV [8192][3456]: 1 block = (b,h,64-row Q tile) -------
__global__ __launch_bounds__(256) void k_attn(const u16* __restrict__ QKV, u16* __restrict__ O) {
  const int tid = threadIdx.x;
  const int w = tid >> 6, lane = tid & 63;
  const int lr = lane & 15, kg = lane >> 4;
  const int bx = blockIdx.x;
  const int qt = bx & 15, h = (bx >> 4) & 15, b = bx >> 8;

  __shared__ u16 lQ[64][104];   // [qrow][d], d zero-padded 72..95
  __shared__ u16 lK[64][104];
  __shared__ u16 lVt[80][72];   // [d][kv] transposed; rows 72..79 zeroed
  __shared__ u16 lP[4][16][72];

  const size_t base = (size_t)b * 1024 * 3456 + h * 72;
  const u16* Q = QKV + base;
  const u16* Kb = QKV + base + 1152;
  const u16* Vb = QKV + base + 2304;

  for (int L = tid; L < 576; L += 256) {
    int r = L / 9, s = L % 9;
    *(uint4*)&lQ[r][s * 8] = *(const uint4*)(Q + (size_t)(qt * 64 + r) * 3456 + s * 8);
  }
  for (int L = tid; L < 192; L += 256) {
    int r = L / 3, s = L % 3;
    *(uint4*)&lQ[r][72 + s * 8] = make_uint4(0, 0, 0, 0);
  }
  for (int L = tid; L < 512; L += 256) lVt[72 + (L >> 6)][L & 63] = 0;
  __syncthreads();

  bf16x8 aq[3];
  #pragma unroll
  for (int ks = 0; ks < 3; ++ks) aq[ks] = *(const bf16x8*)&lQ[w * 16 + lr][ks * 32 + kg * 8];

  float mrun[4], lrun[4];
  f32x4 oacc[5];
  #pragma unroll
  for (int r = 0; r < 4; ++r) { mrun[r] = -1e30f; lrun[r] = 0.f; }
  #pragma unroll
  for (int nd = 0; nd < 5; ++nd) oacc[nd] = f32x4{0.f, 0.f, 0.f, 0.f};

  for (int kt = 0; kt < 16; ++kt) {
    __syncthreads();
    for (int L = tid; L < 576; L += 256) {
      int r = L / 9, s = L % 9;
      *(uint4*)&lK[r][s * 8] = *(const uint4*)(Kb + (size_t)(kt * 64 + r) * 3456 + s * 8);
    }
    for (int L = tid; L < 192; L += 256) {
      int r = L / 3, s = L % 3;
      *(uint4*)&lK[r][72 + s * 8] = make_uint4(0, 0, 0, 0);
    }
    for (int L = tid; L < 576; L += 256) {
      int r = L / 9, s = L % 9;
      uint4 raw = *(const uint4*)(Vb + (size_t)(kt * 64 + r) * 3456 + s * 8);
      const u16* e = (const u16*)&raw;
      #pragma unroll
      for (int j = 0; j < 8; ++j) lVt[s * 8 + j][r] = e[j];
    }
    __syncthreads();

    f32x4 sfr[4];
    #pragma unroll
    for (int kb = 0; kb < 4; ++kb) {
      f32x4 sv = f32x4{0.f, 0.f, 0.f, 0.f};
      #pragma unroll
      for (int ks = 0; ks < 3; ++ks) {
        bf16x8 bk = *(const bf16x8*)&lK[kb * 16 + lr][ks * 32 + kg * 8];
        sv = MFMA16(aq[ks], bk, sv);
      }
      sfr[kb] = sv;
    }
    const float scale = 0.11785113019775793f;  // 1/sqrt(72)
    #pragma unroll
    for (int kb = 0; kb < 4; ++kb)
      #pragma unroll
      for (int r = 0; r < 4; ++r) sfr[kb][r] *= scale;

    float pm[4], al[4];
    #pragma unroll
    for (int r = 0; r < 4; ++r) {
      float x = fmaxf(fmaxf(sfr[0][r], sfr[1][r]), fmaxf(sfr[2][r], sfr[3][r]));
      #pragma unroll
      for (int m = 1; m < 16; m <<= 1) x = fmaxf(x, __shfl_xor(x, m, 16));
      float mn = fmaxf(mrun[r], x);
      al[r] = __expf(mrun[r] - mn);
      mrun[r] = mn;
      pm[r] = mn;
    }
    float rsum[4] = {0.f, 0.f, 0.f, 0.f};
    #pragma unroll
    for (int kb = 0; kb < 4; ++kb)
      #pragma unroll
      for (int r = 0; r < 4; ++r) {
        float p = __expf(sfr[kb][r] - pm[r]);
        rsum[r] += p;
        lP[w][kg * 4 + r][kb * 16 + lr] = f2bf(p);
      }
    #pragma unroll
    for (int r = 0; r < 4; ++r) {
      float t = rsum[r];
      #pragma unroll
      for (int m = 1; m < 16; m <<= 1) t += __shfl_xor(t, m, 16);
      lrun[r] = lrun[r] * al[r] + t;
    }
    #pragma unroll
    for (int nd = 0; nd < 5; ++nd)
      #pragma unroll
      for (int r = 0; r < 4; ++r) oacc[nd][r] *= al[r];

    #pragma unroll
    for (int kstep = 0; kstep < 2; ++kstep) {
      bf16x8 pa = *(const bf16x8*)&lP[w][lr][kstep * 32 + kg * 8];
      #pragma unroll
      for (int nd = 0; nd < 5; ++nd) {
        bf16x8 bv = *(const bf16x8*)&lVt[nd * 16 + lr][kstep * 32 + kg * 8];
        oacc[nd] = MFMA16(pa, bv, oacc[nd]);
      }
    }
  }

  #pragma unroll
  for (int nd = 0; nd < 5; ++nd)
    #pragma unroll
    for (int r = 0; r < 4; ++r) {
      int d = nd * 16 + lr;
      if (d < 72) {
        size_t row = (size_t)b * 1024 + qt * 64 + w * 16 + kg * 4 + r;
        O[row * 1152 + h * 72 + d] = f2bf(oacc[nd][r] / lrun[r]);
      }
    }
}

extern "C" void kernel_launch(void* const* d_in, const int* in_sizes, int n_in,
                              void* d_out, int out_size, void* d_ws, size_t ws_size,
                              hipStream_t stream) {
  const float* x     = (const float*)d_in[0];
  const float* c     = (const float*)d_in[1];
  const float* ln1_w = (const float*)d_in[2];
  const float* ln1_b = (const float*)d_in[3];
  const float* wq    = (const float*)d_in[4];
  const float* wk    = (const float*)d_in[5];
  const float* wv    = (const float*)d_in[6];
  const float* wo    = (const float*)d_in[7];
  const float* wo_b  = (const float*)d_in[8];
  const float* ln2_w = (const float*)d_in[9];
  const float* ln2_b = (const float*)d_in[10];
  const float* fc1_w = (const float*)d_in[11];
  const float* fc1_b = (const float*)d_in[12];
  const float* fc2_w = (const float*)d_in[13];
  const float* fc2_b = (const float*)d_in[14];
  const float* ada_w = (const float*)d_in[15];
  const float* ada_b = (const float*)d_in[16];
  float* out = (float*)d_out;

  char* base = (char*)d_ws;
  size_t off = 0;
  auto alloc = [&](size_t nbytes) -> void* {
    void* p = base + off;
    off += (nbytes + 255) & ~(size_t)255;
    return p;
  };
  const size_t MD = 8192ull * 1152;
  float* silu_c = (float*)alloc(9216 * 4);
  float* partial = (float*)alloc(64ull * 6912 * 4);
  float* modb   = (float*)alloc(55296 * 4);
  u16* qkvT = (u16*)alloc(3456ull * 1152 * 2);   // [wq^T; wk^T; wv^T]
  u16* woT  = (u16*)alloc(1152ull * 1152 * 2);
  u16* fc1T = (u16*)alloc(4608ull * 1152 * 2);
  u16* fc2T = (u16*)alloc(1152ull * 4608 * 2);
  u16* hbuf = (u16*)alloc(MD * 2);               // h -> attnO -> h2
  float* x1 = (float*)alloc(MD * 4);
  u16* big  = (u16*)alloc(8192ull * 4608 * 2);   // qkv then m1
  u16* qkv = big;
  u16* m1 = big;

  k_silu<<<36, 256, 0, stream>>>(c, silu_c, 9216);
  k_modproj1<<<dim3(27, 8), 256, 0, stream>>>(silu_c, ada_w, partial);
  k_modproj2<<<27, 256, 0, stream>>>(partial, ada_b, modb);
  k_tcvt<<<dim3(36, 36), 256, 0, stream>>>(wq, qkvT, 1152, 1152);
  k_tcvt<<<dim3(36, 36), 256, 0, stream>>>(wk, qkvT + 1152ull * 1152, 1152, 1152);
  k_tcvt<<<dim3(36, 36), 256, 0, stream>>>(wv, qkvT + 2304ull * 1152, 1152, 1152);
  k_tcvt<<<dim3(36, 36), 256, 0, stream>>>(wo, woT, 1152, 1152);
  k_tcvt<<<dim3(144, 36), 256, 0, stream>>>(fc1_w, fc1T, 1152, 4608);
  k_tcvt<<<dim3(36, 144), 256, 0, stream>>>(fc2_w, fc2T, 4608, 1152);

  // h = modulate(LN(x), sh_msa, sc_msa)
  k_lnmod<<<8192, 256, 0, stream>>>(x, ln1_w, ln1_b, modb, 0, 1152, hbuf);
  // qkv = h @ [wq wk wv]   (N=3456)
  k_gemm<0><<<dim3(27, 64), 256, 0, stream>>>(hbuf, qkvT, 1152, qkv, nullptr, nullptr, nullptr, nullptr, 0);
  // attention -> O (reuse hbuf)
  k_attn<<<2048, 256, 0, stream>>>(qkv, hbuf);
  // x1 = x + g_msa*(O@wo + wo_b)
  k_gemm<1><<<dim3(9, 64), 256, 0, stream>>>(hbuf, woT, 1152, nullptr, x1, wo_b, x, modb, 2304);
  // h2 = modulate(LN(x1), sh_mlp, sc_mlp)
  k_lnmod<<<8192, 256, 0, stream>>>(x1, ln2_w, ln2_b, modb, 3456, 4608, hbuf);
  // m1 = gelu(h2@fc1 + fc1_b)
  k_gemm<2><<<dim3(36, 64), 256, 0, stream>>>(hbuf, fc1T, 1152, m1, nullptr, fc1_b, nullptr, nullptr, 0);
  // out = x1 + g_mlp*(m1@fc2 + fc2_b)
  k_gemm<1><<<dim3(9, 64), 256, 0, stream>>>(m1, fc2T, 4608, nullptr, out, fc2_b, x1, modb, 5760);
}

// Round 3
// 705.830 us; speedup vs baseline: 1.3688x; 1.1698x over previous
//
#include <hip/hip_runtime.h>
#include <hip/hip_bf16.h>

// DiT block: B=8, S=1024, D=1152, H=16, HD=72, HID=4608
// GEMMs: bf16 MFMA 16x16x32, f32 accum, 128x128 tile, BK=32, global_load_lds.
// Attention: swapped QK^T (S^T layout -> in-lane softmax), V pre-transposed by
// the QKV GEMM epilogue, P via packed-u32 wave-private LDS.

typedef unsigned short u16;
typedef unsigned int u32;
typedef __attribute__((ext_vector_type(8))) short bf16x8;
typedef __attribute__((ext_vector_type(4))) float f32x4;

#define MFMA16(a, b, c) __builtin_amdgcn_mfma_f32_16x16x32_bf16((a), (b), (c), 0, 0, 0)

__device__ __forceinline__ u16 f2bf(float f) {
  __hip_bfloat16 h = __float2bfloat16(f);
  return __builtin_bit_cast(u16, h);
}

__device__ __forceinline__ void gload16(const u16* g, u16* l) {
  __builtin_amdgcn_global_load_lds(
      (const __attribute__((address_space(1))) unsigned int*)(const void*)g,
      (__attribute__((address_space(3))) unsigned int*)(void*)l, 16, 0, 0);
}

// ---------------- silu(c) ----------------
__global__ void k_silu(const float* __restrict__ c, float* __restrict__ o, int n) {
  int i = blockIdx.x * 256 + threadIdx.x;
  if (i < n) { float v = c[i]; o[i] = v / (1.f + __expf(-v)); }
}

// ------- mod projection, split-K stage 1 -------
__global__ __launch_bounds__(256) void k_modproj1(const float* __restrict__ sc,
                                                  const float* __restrict__ aw,
                                                  float* __restrict__ partial) {
  __shared__ float lc[8][144];
  int kc = blockIdx.y;
  for (int i = threadIdx.x; i < 1152; i += 256) {
    int b = i / 144, k = i % 144;
    lc[b][k] = sc[b * 1152 + kc * 144 + k];
  }
  __syncthreads();
  int j = blockIdx.x * 256 + threadIdx.x;
  float acc[8] = {0, 0, 0, 0, 0, 0, 0, 0};
  for (int k = 0; k < 144; ++k) {
    float w = aw[(size_t)(kc * 144 + k) * 6912 + j];
    #pragma unroll
    for (int b = 0; b < 8; ++b) acc[b] += lc[b][k] * w;
  }
  #pragma unroll
  for (int b = 0; b < 8; ++b) partial[((size_t)kc * 8 + b) * 6912 + j] = acc[b];
}

// ------- mod projection stage 2 -------
__global__ __launch_bounds__(256) void k_modproj2(const float* __restrict__ partial,
                                                  const float* __restrict__ ab,
                                                  float* __restrict__ mo) {
  int j = blockIdx.x * 256 + threadIdx.x;
  float bias = ab[j];
  #pragma unroll
  for (int b = 0; b < 8; ++b) {
    float s = 0.f;
    #pragma unroll
    for (int kc = 0; kc < 8; ++kc) s += partial[((size_t)kc * 8 + b) * 6912 + j];
    mo[(size_t)b * 6912 + j] = s + bias;
  }
}

// ------- transpose-convert: in[K][N] f32 -> out[N][K] bf16 -------
__global__ __launch_bounds__(256) void k_tcvt(const float* __restrict__ in, u16* __restrict__ out,
                                              int K, int N) {
  __shared__ float t[32][33];
  int tx = threadIdx.x & 31, ty = threadIdx.x >> 5;
  size_t bx = (size_t)blockIdx.x * 32, by = (size_t)blockIdx.y * 32;
  #pragma unroll
  for (int i = 0; i < 4; ++i) t[ty + 8 * i][tx] = in[(by + ty + 8 * i) * N + bx + tx];
  __syncthreads();
  #pragma unroll
  for (int i = 0; i < 4; ++i) out[(bx + ty + 8 * i) * K + by + tx] = f2bf(t[tx][ty + 8 * i]);
}

// ------- fused LayerNorm + modulate -> bf16 row -------
__global__ __launch_bounds__(256) void k_lnmod(const float* __restrict__ xin,
                                               const float* __restrict__ w,
                                               const float* __restrict__ bs,
                                               const float* __restrict__ mo,
                                               int sh_off, int sc_off, u16* __restrict__ o) {
  int row = blockIdx.x;
  int b = row >> 10;
  int tid = threadIdx.x;
  const float4* x4 = (const float4*)(xin + (size_t)row * 1152);
  float4 v0 = x4[tid];
  float4 v1 = make_float4(0.f, 0.f, 0.f, 0.f);
  if (tid < 32) v1 = x4[256 + tid];
  float s = v0.x + v0.y + v0.z + v0.w + v1.x + v1.y + v1.z + v1.w;
  float sq = v0.x * v0.x + v0.y * v0.y + v0.z * v0.z + v0.w * v0.w +
             v1.x * v1.x + v1.y * v1.y + v1.z * v1.z + v1.w * v1.w;
  #pragma unroll
  for (int d = 32; d > 0; d >>= 1) { s += __shfl_down(s, d); sq += __shfl_down(sq, d); }
  __shared__ float ps[4], pq[4];
  int wid = tid >> 6, lane = tid & 63;
  if (lane == 0) { ps[wid] = s; pq[wid] = sq; }
  __syncthreads();
  float S = ps[0] + ps[1] + ps[2] + ps[3];
  float SQ = pq[0] + pq[1] + pq[2] + pq[3];
  float mean = S * (1.f / 1152.f);
  float var = SQ * (1.f / 1152.f) - mean * mean;
  float rs = rsqrtf(var + 1e-5f);
  const float* shp = mo + (size_t)b * 6912 + sh_off;
  const float* scp = mo + (size_t)b * 6912 + sc_off;
  u16* orow = o + (size_t)row * 1152;
  {
    int col = 4 * tid;
    ushort4 u; float y;
    y = (v0.x - mean) * rs * w[col + 0] + bs[col + 0]; u.x = f2bf(y * (1.f + scp[col + 0]) + shp[col + 0]);
    y = (v0.y - mean) * rs * w[col + 1] + bs[col + 1]; u.y = f2bf(y * (1.f + scp[col + 1]) + shp[col + 1]);
    y = (v0.z - mean) * rs * w[col + 2] + bs[col + 2]; u.z = f2bf(y * (1.f + scp[col + 2]) + shp[col + 2]);
    y = (v0.w - mean) * rs * w[col + 3] + bs[col + 3]; u.w = f2bf(y * (1.f + scp[col + 3]) + shp[col + 3]);
    *(ushort4*)&orow[col] = u;
  }
  if (tid < 32) {
    int col = 1024 + 4 * tid;
    ushort4 u; float y;
    y = (v1.x - mean) * rs * w[col + 0] + bs[col + 0]; u.x = f2bf(y * (1.f + scp[col + 0]) + shp[col + 0]);
    y = (v1.y - mean) * rs * w[col + 1] + bs[col + 1]; u.y = f2bf(y * (1.f + scp[col + 1]) + shp[col + 1]);
    y = (v1.z - mean) * rs * w[col + 2] + bs[col + 2]; u.z = f2bf(y * (1.f + scp[col + 2]) + shp[col + 2]);
    y = (v1.w - mean) * rs * w[col + 3] + bs[col + 3]; u.w = f2bf(y * (1.f + scp[col + 3]) + shp[col + 3]);
    *(ushort4*)&orow[col] = u;
  }
}

// ------- bf16 MFMA GEMM, m97 structure -------
// EPI 1: Cf = res + mod*(acc+bias); EPI 2: Cb = bf16(gelu(acc+bias));
// EPI 3: QKV -> Q,K rows normal into Cb; V region transposed into vt[b,h,d,s]
template <int EPI>
__global__ __launch_bounds__(256) void k_gemm(const u16* __restrict__ A, const u16* __restrict__ Bt,
                                              int K, u16* __restrict__ Cb, float* __restrict__ Cf,
                                              const float* __restrict__ bias,
                                              const float* __restrict__ res,
                                              const float* __restrict__ mo, int goff,
                                              u16* __restrict__ vt) {
  const int tid = threadIdx.x;
  const int w = tid >> 6, lane = tid & 63;
  const int wr = w >> 1, wc = w & 1;
  const int lr = lane & 15, kg = lane >> 4;

  const int nwg = gridDim.x * gridDim.y;
  const int id = blockIdx.y * gridDim.x + blockIdx.x;
  const int swz = (id & 7) * (nwg >> 3) + (id >> 3);
  const int tM = (swz / gridDim.x) * 128, tN = (swz % gridDim.x) * 128;
  const int N = gridDim.x * 128;

  __shared__ u16 lA[128 * 32];
  __shared__ u16 lB[128 * 32];
  f32x4 acc[4][4];
  #pragma unroll
  for (int m = 0; m < 4; ++m)
    #pragma unroll
    for (int n = 0; n < 4; ++n) acc[m][n] = f32x4{0.f, 0.f, 0.f, 0.f};

  const int lrow = lane >> 2, lseg = lane & 3;
  const u16* gA = A + (size_t)(tM + w * 32 + lrow) * K + lseg * 8;
  const u16* gB = Bt + (size_t)(tN + w * 32 + lrow) * K + lseg * 8;
  u16* lA0 = lA + (w * 32) * 32;
  u16* lA1 = lA + (w * 32 + 16) * 32;
  u16* lB0 = lB + (w * 32) * 32;
  u16* lB1 = lB + (w * 32 + 16) * 32;
  const size_t rstep = (size_t)16 * K;

  for (int ks = 0; ks < K; ks += 32) {
    __syncthreads();
    gload16(gA + ks, lA0);
    gload16(gA + rstep + ks, lA1);
    gload16(gB + ks, lB0);
    gload16(gB + rstep + ks, lB1);
    __syncthreads();
    bf16x8 af[4], bfr[4];
    #pragma unroll
    for (int m = 0; m < 4; ++m) af[m] = *(const bf16x8*)&lA[(wr * 64 + m * 16 + lr) * 32 + kg * 8];
    #pragma unroll
    for (int n = 0; n < 4; ++n) bfr[n] = *(const bf16x8*)&lB[(wc * 64 + n * 16 + lr) * 32 + kg * 8];
    #pragma unroll
    for (int m = 0; m < 4; ++m)
      #pragma unroll
      for (int n = 0; n < 4; ++n) acc[m][n] = MFMA16(af[m], bfr[n], acc[m][n]);
  }
  // epilogue: D row=(lane>>4)*4+reg, col=lane&15
  if (EPI == 3) {
    #pragma unroll
    for (int m = 0; m < 4; ++m)
      #pragma unroll
      for (int n = 0; n < 4; ++n) {
        int gcol = tN + wc * 64 + n * 16 + lr;
        int s0 = tM + wr * 64 + m * 16 + kg * 4;
        if (tN < 2304) {
          #pragma unroll
          for (int r = 0; r < 4; ++r) Cb[(size_t)(s0 + r) * N + gcol] = f2bf(acc[m][n][r]);
        } else {
          int qq = gcol - 2304;
          int hh = qq / 72;
          int d = qq - hh * 72;
          int bb = s0 >> 10, sl = s0 & 1023;
          ushort4 u;
          u.x = f2bf(acc[m][n][0]); u.y = f2bf(acc[m][n][1]);
          u.z = f2bf(acc[m][n][2]); u.w = f2bf(acc[m][n][3]);
          *(ushort4*)&vt[(((size_t)bb * 16 + hh) * 72 + d) * 1024 + sl] = u;
        }
      }
  } else {
    #pragma unroll
    for (int m = 0; m < 4; ++m)
      #pragma unroll
      for (int n = 0; n < 4; ++n)
        #pragma unroll
        for (int r = 0; r < 4; ++r) {
          int grow = tM + wr * 64 + m * 16 + kg * 4 + r;
          int gcol = tN + wc * 64 + n * 16 + lr;
          size_t idx = (size_t)grow * N + gcol;
          float v = acc[m][n][r];
          if (EPI == 1) {
            float g = mo[(size_t)(grow >> 10) * 6912 + goff + gcol];
            Cf[idx] = res[idx] + g * (v + bias[gcol]);
          } else {
            float z = v + bias[gcol];
            Cb[idx] = f2bf(0.5f * z * (1.f + erff(z * 0.70710678118f)));
          }
        }
  }
}

// ------- flash attention, swapped-QK^T structure -------
// block = (b, h, 64-row q-tile), 4 waves x 16 q-rows; KV tiles of 64.
__global__ __launch_bounds__(256) void k_attn(const u16* __restrict__ QKV, const u16* __restrict__ Vt,
                                              u16* __restrict__ O) {
  const int tid = threadIdx.x;
  const int w = tid >> 6, lane = tid & 63;
  const int lr = lane & 15, kg = lane >> 4;
  int bx = blockIdx.x;
  bx = (bx & 7) * 256 + (bx >> 3);  // XCD-chunk swizzle: one batch per XCD
  const int qt = bx & 15, h = (bx >> 4) & 15, b = bx >> 8;

  __shared__ u16 lQ[64][104];      // [q][d], cols 72..95 zero
  __shared__ u16 lK[64][104];      // [key][d], cols 72..95 zero
  __shared__ u16 lVt[80][72];      // [d][key], rows 72..79 zero
  __shared__ u16 lPt[4][16][72];   // wave-private [q][key]

  const size_t qkbase = (size_t)b * 1024 * 3456 + (size_t)h * 72;
  const u16* Qg = QKV + qkbase;
  const u16* Kg = QKV + qkbase + 1152;
  const u16* Vg = Vt + ((size_t)(b * 16 + h) * 72) * 1024;

  // zero pads once
  const uint4 z4 = make_uint4(0, 0, 0, 0);
  for (int L = tid; L < 192; L += 256) {
    int r = L / 3, s = L - (L / 3) * 3;
    *(uint4*)&lQ[r][72 + s * 8] = z4;
    *(uint4*)&lK[r][72 + s * 8] = z4;
  }
  for (int L = tid; L < 72; L += 256) {
    int r = L / 9, s = L - (L / 9) * 9;
    *(uint4*)&lVt[72 + r][s * 8] = z4;
  }
  // stage Q (576 uint4)
  {
    int L = tid; int r = L / 9, s = L - r * 9;
    *(uint4*)&lQ[r][s * 8] = *(const uint4*)(Qg + (size_t)(qt * 64 + r) * 3456 + s * 8);
    L = tid + 256; r = L / 9; s = L - r * 9;
    *(uint4*)&lQ[r][s * 8] = *(const uint4*)(Qg + (size_t)(qt * 64 + r) * 3456 + s * 8);
    if (tid < 64) {
      L = tid + 512; r = L / 9; s = L - r * 9;
      *(uint4*)&lQ[r][s * 8] = *(const uint4*)(Qg + (size_t)(qt * 64 + r) * 3456 + s * 8);
    }
  }
  __syncthreads();

  bf16x8 bq[3];
  #pragma unroll
  for (int ks = 0; ks < 3; ++ks) bq[ks] = *(const bf16x8*)&lQ[w * 16 + lr][ks * 32 + kg * 8];

  const float scale = 0.11785113019775793f;  // 1/sqrt(72)
  float mrun = -1e30f, lrun = 0.f;
  f32x4 oacc[5];
  #pragma unroll
  for (int nd = 0; nd < 5; ++nd) oacc[nd] = f32x4{0.f, 0.f, 0.f, 0.f};

  for (int kt = 0; kt < 16; ++kt) {
    __syncthreads();
    {
      int L = tid; int r = L / 9, s = L - (L / 9) * 9;
      *(uint4*)&lK[r][s * 8] = *(const uint4*)(Kg + (size_t)(kt * 64 + r) * 3456 + s * 8);
      int d = tid >> 3, sg = tid & 7;
      *(uint4*)&lVt[d][sg * 8] = *(const uint4*)(Vg + (size_t)d * 1024 + kt * 64 + sg * 8);
      L = tid + 256; r = L / 9; s = L - r * 9;
      *(uint4*)&lK[r][s * 8] = *(const uint4*)(Kg + (size_t)(kt * 64 + r) * 3456 + s * 8);
      d = (tid + 256) >> 3; sg = tid & 7;
      *(uint4*)&lVt[d][sg * 8] = *(const uint4*)(Vg + (size_t)d * 1024 + kt * 64 + sg * 8);
      if (tid < 64) {
        L = tid + 512; r = L / 9; s = L - r * 9;
        *(uint4*)&lK[r][s * 8] = *(const uint4*)(Kg + (size_t)(kt * 64 + r) * 3456 + s * 8);
        d = (tid + 512) >> 3;
        *(uint4*)&lVt[d][sg * 8] = *(const uint4*)(Vg + (size_t)d * 1024 + kt * 64 + sg * 8);
      }
    }
    __syncthreads();

    // S^T = K @ Q^T: lane (lr,kg) -> S[q=w*16+lr][key = kb*16 + kg*4 + r]
    f32x4 sfr[4];
    __builtin_amdgcn_s_setprio(1);
    #pragma unroll
    for (int kb = 0; kb < 4; ++kb) {
      f32x4 sv = f32x4{0.f, 0.f, 0.f, 0.f};
      #pragma unroll
      for (int ks = 0; ks < 3; ++ks) {
        bf16x8 ak = *(const bf16x8*)&lK[kb * 16 + lr][ks * 32 + kg * 8];
        sv = MFMA16(ak, bq[ks], sv);
      }
      sfr[kb] = sv;
    }
    __builtin_amdgcn_s_setprio(0);

    // in-lane softmax over this lane's 16 keys, reduce across kg groups
    float mx = sfr[0][0];
    #pragma unroll
    for (int kb = 0; kb < 4; ++kb)
      #pragma unroll
      for (int r = 0; r < 4; ++r) mx = fmaxf(mx, sfr[kb][r]);
    mx = fmaxf(mx, __shfl_xor(mx, 16));
    mx = fmaxf(mx, __shfl_xor(mx, 32));
    mx *= scale;
    float mn = fmaxf(mrun, mx);
    float al = __expf(mrun - mn);
    mrun = mn;
    float sum = 0.f;
    #pragma unroll
    for (int kb = 0; kb < 4; ++kb) {
      #pragma unroll
      for (int rp = 0; rp < 2; ++rp) {
        float p0 = __expf(__fmaf_rn(sfr[kb][2 * rp], scale, -mn));
        float p1 = __expf(__fmaf_rn(sfr[kb][2 * rp + 1], scale, -mn));
        sum += p0 + p1;
        u32 pk = (u32)f2bf(p0) | ((u32)f2bf(p1) << 16);
        *(u32*)&lPt[w][lr][kb * 16 + kg * 4 + rp * 2] = pk;
      }
    }
    sum += __shfl_xor(sum, 16);
    sum += __shfl_xor(sum, 32);
    lrun = lrun * al + sum;
    #pragma unroll
    for (int nd = 0; nd < 5; ++nd)
      #pragma unroll
      for (int r = 0; r < 4; ++r) oacc[nd][r] *= al;

    // O^T += Vt @ P^T : lane (lr,kg) -> O^T[d = nd*16 + kg*4 + r][q = w*16+lr]
    __builtin_amdgcn_s_setprio(1);
    #pragma unroll
    for (int s = 0; s < 2; ++s) {
      bf16x8 bp = *(const bf16x8*)&lPt[w][lr][s * 32 + kg * 8];
      #pragma unroll
      for (int nd = 0; nd < 5; ++nd) {
        bf16x8 av = *(const bf16x8*)&lVt[nd * 16 + lr][s * 32 + kg * 8];
        oacc[nd] = MFMA16(av, bp, oacc[nd]);
      }
    }
    __builtin_amdgcn_s_setprio(0);
  }

  float inv = 1.f / lrun;
  size_t orow = ((size_t)b * 1024 + qt * 64 + w * 16 + lr) * 1152 + h * 72;
  #pragma unroll
  for (int nd = 0; nd < 5; ++nd) {
    int d0 = nd * 16 + kg * 4;
    if (d0 < 72) {
      ushort4 u;
      u.x = f2bf(oacc[nd][0] * inv);
      u.y = f2bf(oacc[nd][1] * inv);
      u.z = f2bf(oacc[nd][2] * inv);
      u.w = f2bf(oacc[nd][3] * inv);
      *(ushort4*)&O[orow + d0] = u;
    }
  }
}

extern "C" void kernel_launch(void* const* d_in, const int* in_sizes, int n_in,
                              void* d_out, int out_size, void* d_ws, size_t ws_size,
                              hipStream_t stream) {
  const float* x     = (const float*)d_in[0];
  const float* c     = (const float*)d_in[1];
  const float* ln1_w = (const float*)d_in[2];
  const float* ln1_b = (const float*)d_in[3];
  const float* wq    = (const float*)d_in[4];
  const float* wk    = (const float*)d_in[5];
  const float* wv    = (const float*)d_in[6];
  const float* wo    = (const float*)d_in[7];
  const float* wo_b  = (const float*)d_in[8];
  const float* ln2_w = (const float*)d_in[9];
  const float* ln2_b = (const float*)d_in[10];
  const float* fc1_w = (const float*)d_in[11];
  const float* fc1_b = (const float*)d_in[12];
  const float* fc2_w = (const float*)d_in[13];
  const float* fc2_b = (const float*)d_in[14];
  const float* ada_w = (const float*)d_in[15];
  const float* ada_b = (const float*)d_in[16];
  float* out = (float*)d_out;

  char* base = (char*)d_ws;
  size_t off = 0;
  auto alloc = [&](size_t nbytes) -> void* {
    void* p = base + off;
    off += (nbytes + 255) & ~(size_t)255;
    return p;
  };
  const size_t MD = 8192ull * 1152;
  float* silu_c = (float*)alloc(9216 * 4);
  float* partial = (float*)alloc(64ull * 6912 * 4);
  float* modb   = (float*)alloc(55296 * 4);
  u16* qkvT = (u16*)alloc(3456ull * 1152 * 2);
  u16* woT  = (u16*)alloc(1152ull * 1152 * 2);
  u16* fc1T = (u16*)alloc(4608ull * 1152 * 2);
  u16* fc2T = (u16*)alloc(1152ull * 4608 * 2);
  u16* hbuf = (u16*)alloc(MD * 2);               // h -> attnO -> h2
  float* x1 = (float*)alloc(MD * 4);
  u16* vtb  = (u16*)alloc(128ull * 72 * 1024 * 2);  // V transposed [b,h,d,s]
  u16* big  = (u16*)alloc(8192ull * 4608 * 2);   // qkv (Q,K used) then m1
  u16* qkv = big;
  u16* m1 = big;

  k_silu<<<36, 256, 0, stream>>>(c, silu_c, 9216);
  k_modproj1<<<dim3(27, 8), 256, 0, stream>>>(silu_c, ada_w, partial);
  k_modproj2<<<27, 256, 0, stream>>>(partial, ada_b, modb);
  k_tcvt<<<dim3(36, 36), 256, 0, stream>>>(wq, qkvT, 1152, 1152);
  k_tcvt<<<dim3(36, 36), 256, 0, stream>>>(wk, qkvT + 1152ull * 1152, 1152, 1152);
  k_tcvt<<<dim3(36, 36), 256, 0, stream>>>(wv, qkvT + 2304ull * 1152, 1152, 1152);
  k_tcvt<<<dim3(36, 36), 256, 0, stream>>>(wo, woT, 1152, 1152);
  k_tcvt<<<dim3(144, 36), 256, 0, stream>>>(fc1_w, fc1T, 1152, 4608);
  k_tcvt<<<dim3(36, 144), 256, 0, stream>>>(fc2_w, fc2T, 4608, 1152);

  // h = modulate(LN(x), sh_msa, sc_msa)
  k_lnmod<<<8192, 256, 0, stream>>>(x, ln1_w, ln1_b, modb, 0, 1152, hbuf);
  // qkv: Q,K rows into qkv buffer, V transposed into vtb
  k_gemm<3><<<dim3(27, 64), 256, 0, stream>>>(hbuf, qkvT, 1152, qkv, nullptr, nullptr, nullptr, nullptr, 0, vtb);
  // attention -> O (reuse hbuf)
  k_attn<<<2048, 256, 0, stream>>>(qkv, vtb, hbuf);
  // x1 = x + g_msa*(O@wo + wo_b)
  k_gemm<1><<<dim3(9, 64), 256, 0, stream>>>(hbuf, woT, 1152, nullptr, x1, wo_b, x, modb, 2304, nullptr);
  // h2 = modulate(LN(x1), sh_mlp, sc_mlp)
  k_lnmod<<<8192, 256, 0, stream>>>(x1, ln2_w, ln2_b, modb, 3456, 4608, hbuf);
  // m1 = gelu(h2@fc1 + fc1_b)
  k_gemm<2><<<dim3(36, 64), 256, 0, stream>>>(hbuf, fc1T, 1152, m1, nullptr, fc1_b, nullptr, nullptr, 0, nullptr);
  // out = x1 + g_mlp*(m1@fc2 + fc2_b)
  k_gemm<1><<<dim3(9, 64), 256, 0, stream>>>(m1, fc2T, 4608, nullptr, out, fc2_b, x1, modb, 5760, nullptr);
}

// Round 4
// 665.863 us; speedup vs baseline: 1.4510x; 1.0600x over previous
//
#include <hip/hip_runtime.h>
#include <hip/hip_bf16.h>

// DiT block: B=8, S=1024, D=1152, H=16, HD=72, HID=4608
// GEMMs: bf16 MFMA 16x16x32, f32 accum, 128x128 tile, BK=32, global_load_lds,
// 2-phase double-buffered pipeline (stage t+1 before compute t, one barrier/step).
// fc2 split-K x2 with fused reduce. Attention: swapped QK^T, pre-transposed V.

typedef unsigned short u16;
typedef unsigned int u32;
typedef __attribute__((ext_vector_type(8))) short bf16x8;
typedef __attribute__((ext_vector_type(4))) float f32x4;

#define MFMA16(a, b, c) __builtin_amdgcn_mfma_f32_16x16x32_bf16((a), (b), (c), 0, 0, 0)

__device__ __forceinline__ u16 f2bf(float f) {
  __hip_bfloat16 h = __float2bfloat16(f);
  return __builtin_bit_cast(u16, h);
}

__device__ __forceinline__ void gload16(const u16* g, u16* l) {
  __builtin_amdgcn_global_load_lds(
      (const __attribute__((address_space(1))) unsigned int*)(const void*)g,
      (__attribute__((address_space(3))) unsigned int*)(void*)l, 16, 0, 0);
}

// ---------------- silu(c) ----------------
__global__ void k_silu(const float* __restrict__ c, float* __restrict__ o, int n) {
  int i = blockIdx.x * 256 + threadIdx.x;
  if (i < n) { float v = c[i]; o[i] = v / (1.f + __expf(-v)); }
}

// ------- mod projection, split-K stage 1 -------
__global__ __launch_bounds__(256) void k_modproj1(const float* __restrict__ sc,
                                                  const float* __restrict__ aw,
                                                  float* __restrict__ partial) {
  __shared__ float lc[8][144];
  int kc = blockIdx.y;
  for (int i = threadIdx.x; i < 1152; i += 256) {
    int b = i / 144, k = i % 144;
    lc[b][k] = sc[b * 1152 + kc * 144 + k];
  }
  __syncthreads();
  int j = blockIdx.x * 256 + threadIdx.x;
  float acc[8] = {0, 0, 0, 0, 0, 0, 0, 0};
  for (int k = 0; k < 144; ++k) {
    float w = aw[(size_t)(kc * 144 + k) * 6912 + j];
    #pragma unroll
    for (int b = 0; b < 8; ++b) acc[b] += lc[b][k] * w;
  }
  #pragma unroll
  for (int b = 0; b < 8; ++b) partial[((size_t)kc * 8 + b) * 6912 + j] = acc[b];
}

// ------- mod projection stage 2 -------
__global__ __launch_bounds__(256) void k_modproj2(const float* __restrict__ partial,
                                                  const float* __restrict__ ab,
                                                  float* __restrict__ mo) {
  int j = blockIdx.x * 256 + threadIdx.x;
  float bias = ab[j];
  #pragma unroll
  for (int b = 0; b < 8; ++b) {
    float s = 0.f;
    #pragma unroll
    for (int kc = 0; kc < 8; ++kc) s += partial[((size_t)kc * 8 + b) * 6912 + j];
    mo[(size_t)b * 6912 + j] = s + bias;
  }
}

// ------- transpose-convert: in[K][N] f32 -> out[N][K] bf16 -------
__global__ __launch_bounds__(256) void k_tcvt(const float* __restrict__ in, u16* __restrict__ out,
                                              int K, int N) {
  __shared__ float t[32][33];
  int tx = threadIdx.x & 31, ty = threadIdx.x >> 5;
  size_t bx = (size_t)blockIdx.x * 32, by = (size_t)blockIdx.y * 32;
  #pragma unroll
  for (int i = 0; i < 4; ++i) t[ty + 8 * i][tx] = in[(by + ty + 8 * i) * N + bx + tx];
  __syncthreads();
  #pragma unroll
  for (int i = 0; i < 4; ++i) out[(bx + ty + 8 * i) * K + by + tx] = f2bf(t[tx][ty + 8 * i]);
}

// ------- fused LayerNorm + modulate -> bf16 row -------
__global__ __launch_bounds__(256) void k_lnmod(const float* __restrict__ xin,
                                               const float* __restrict__ w,
                                               const float* __restrict__ bs,
                                               const float* __restrict__ mo,
                                               int sh_off, int sc_off, u16* __restrict__ o) {
  int row = blockIdx.x;
  int b = row >> 10;
  int tid = threadIdx.x;
  const float4* x4 = (const float4*)(xin + (size_t)row * 1152);
  float4 v0 = x4[tid];
  float4 v1 = make_float4(0.f, 0.f, 0.f, 0.f);
  if (tid < 32) v1 = x4[256 + tid];
  float s = v0.x + v0.y + v0.z + v0.w + v1.x + v1.y + v1.z + v1.w;
  float sq = v0.x * v0.x + v0.y * v0.y + v0.z * v0.z + v0.w * v0.w +
             v1.x * v1.x + v1.y * v1.y + v1.z * v1.z + v1.w * v1.w;
  #pragma unroll
  for (int d = 32; d > 0; d >>= 1) { s += __shfl_down(s, d); sq += __shfl_down(sq, d); }
  __shared__ float ps[4], pq[4];
  int wid = tid >> 6, lane = tid & 63;
  if (lane == 0) { ps[wid] = s; pq[wid] = sq; }
  __syncthreads();
  float S = ps[0] + ps[1] + ps[2] + ps[3];
  float SQ = pq[0] + pq[1] + pq[2] + pq[3];
  float mean = S * (1.f / 1152.f);
  float var = SQ * (1.f / 1152.f) - mean * mean;
  float rs = rsqrtf(var + 1e-5f);
  const float* shp = mo + (size_t)b * 6912 + sh_off;
  const float* scp = mo + (size_t)b * 6912 + sc_off;
  u16* orow = o + (size_t)row * 1152;
  {
    int col = 4 * tid;
    ushort4 u; float y;
    y = (v0.x - mean) * rs * w[col + 0] + bs[col + 0]; u.x = f2bf(y * (1.f + scp[col + 0]) + shp[col + 0]);
    y = (v0.y - mean) * rs * w[col + 1] + bs[col + 1]; u.y = f2bf(y * (1.f + scp[col + 1]) + shp[col + 1]);
    y = (v0.z - mean) * rs * w[col + 2] + bs[col + 2]; u.z = f2bf(y * (1.f + scp[col + 2]) + shp[col + 2]);
    y = (v0.w - mean) * rs * w[col + 3] + bs[col + 3]; u.w = f2bf(y * (1.f + scp[col + 3]) + shp[col + 3]);
    *(ushort4*)&orow[col] = u;
  }
  if (tid < 32) {
    int col = 1024 + 4 * tid;
    ushort4 u; float y;
    y = (v1.x - mean) * rs * w[col + 0] + bs[col + 0]; u.x = f2bf(y * (1.f + scp[col + 0]) + shp[col + 0]);
    y = (v1.y - mean) * rs * w[col + 1] + bs[col + 1]; u.y = f2bf(y * (1.f + scp[col + 1]) + shp[col + 1]);
    y = (v1.z - mean) * rs * w[col + 2] + bs[col + 2]; u.z = f2bf(y * (1.f + scp[col + 2]) + shp[col + 2]);
    y = (v1.w - mean) * rs * w[col + 3] + bs[col + 3]; u.w = f2bf(y * (1.f + scp[col + 3]) + shp[col + 3]);
    *(ushort4*)&orow[col] = u;
  }
}

// ------- bf16 MFMA GEMM, 2-phase double-buffered (T3-min) -------
// C[M,N] = A[M,Kst](cols koff..koff+klen) @ Bt[N,Kst]^T
// EPI 1: Cf = res + mod*(acc+bias); EPI 2: Cb = bf16(gelu(acc+bias));
// EPI 3: QKV (Q,K normal; V transposed to vt[b,h,d,s]); EPI 4: raw f32 partial (split-K)
template <int EPI>
__global__ __launch_bounds__(256) void k_gemm(const u16* __restrict__ A, const u16* __restrict__ Bt,
                                              int Kst, int klen, u16* __restrict__ Cb,
                                              float* __restrict__ Cf,
                                              const float* __restrict__ bias,
                                              const float* __restrict__ res,
                                              const float* __restrict__ mo, int goff,
                                              u16* __restrict__ vt) {
  const int tid = threadIdx.x;
  const int w = tid >> 6, lane = tid & 63;
  const int wr = w >> 1, wc = w & 1;
  const int lr = lane & 15, kg = lane >> 4;

  const int nwg = gridDim.x * gridDim.y;
  const int id = blockIdx.y * gridDim.x + blockIdx.x;
  const int swz = (id & 7) * (nwg >> 3) + (id >> 3);
  const int tM = (swz / gridDim.x) * 128, tN = (swz % gridDim.x) * 128;
  const int N = gridDim.x * 128;
  const int koff = blockIdx.z * klen;

  __shared__ u16 lA[2][128 * 32];
  __shared__ u16 lB[2][128 * 32];
  f32x4 acc[4][4];
  #pragma unroll
  for (int m = 0; m < 4; ++m)
    #pragma unroll
    for (int n = 0; n < 4; ++n) acc[m][n] = f32x4{0.f, 0.f, 0.f, 0.f};

  const int lrow = lane >> 2, lseg = lane & 3;
  const u16* gA = A + (size_t)(tM + w * 32 + lrow) * Kst + lseg * 8;
  const u16* gB = Bt + (size_t)(tN + w * 32 + lrow) * Kst + lseg * 8;
  const size_t rstep = (size_t)16 * Kst;
  const int wo0 = (w * 32) * 32, wo1 = (w * 32 + 16) * 32;

  auto stage = [&](int buf, int ks) {
    gload16(gA + ks, lA[buf] + wo0);
    gload16(gA + rstep + ks, lA[buf] + wo1);
    gload16(gB + ks, lB[buf] + wo0);
    gload16(gB + rstep + ks, lB[buf] + wo1);
  };
  auto compute = [&](int buf) {
    bf16x8 af[4], bfr[4];
    #pragma unroll
    for (int m = 0; m < 4; ++m) af[m] = *(const bf16x8*)&lA[buf][(wr * 64 + m * 16 + lr) * 32 + kg * 8];
    #pragma unroll
    for (int n = 0; n < 4; ++n) bfr[n] = *(const bf16x8*)&lB[buf][(wc * 64 + n * 16 + lr) * 32 + kg * 8];
    #pragma unroll
    for (int m = 0; m < 4; ++m)
      #pragma unroll
      for (int n = 0; n < 4; ++n) acc[m][n] = MFMA16(af[m], bfr[n], acc[m][n]);
  };

  // prologue
  stage(0, koff);
  __syncthreads();  // vmcnt(0) drain: tile 0 resident
  int cur = 0;
  for (int ks = koff + 32; ks < koff + klen; ks += 32) {
    stage(cur ^ 1, ks);   // async loads for t+1, in flight across compute
    compute(cur);
    __syncthreads();      // drains vmcnt -> t+1 resident; also guards re-stage of cur
    cur ^= 1;
  }
  compute(cur);

  // epilogue: D row=(lane>>4)*4+reg, col=lane&15
  if (EPI == 3) {
    #pragma unroll
    for (int m = 0; m < 4; ++m)
      #pragma unroll
      for (int n = 0; n < 4; ++n) {
        int gcol = tN + wc * 64 + n * 16 + lr;
        int s0 = tM + wr * 64 + m * 16 + kg * 4;
        if (tN < 2304) {
          #pragma unroll
          for (int r = 0; r < 4; ++r) Cb[(size_t)(s0 + r) * N + gcol] = f2bf(acc[m][n][r]);
        } else {
          int qq = gcol - 2304;
          int hh = qq / 72;
          int d = qq - hh * 72;
          int bb = s0 >> 10, sl = s0 & 1023;
          ushort4 u;
          u.x = f2bf(acc[m][n][0]); u.y = f2bf(acc[m][n][1]);
          u.z = f2bf(acc[m][n][2]); u.w = f2bf(acc[m][n][3]);
          *(ushort4*)&vt[(((size_t)bb * 16 + hh) * 72 + d) * 1024 + sl] = u;
        }
      }
  } else if (EPI == 4) {
    float* Po = Cf + (size_t)blockIdx.z * ((size_t)gridDim.y * 128) * N;
    #pragma unroll
    for (int m = 0; m < 4; ++m)
      #pragma unroll
      for (int n = 0; n < 4; ++n)
        #pragma unroll
        for (int r = 0; r < 4; ++r) {
          int grow = tM + wr * 64 + m * 16 + kg * 4 + r;
          int gcol = tN + wc * 64 + n * 16 + lr;
          Po[(size_t)grow * N + gcol] = acc[m][n][r];
        }
  } else {
    #pragma unroll
    for (int m = 0; m < 4; ++m)
      #pragma unroll
      for (int n = 0; n < 4; ++n)
        #pragma unroll
        for (int r = 0; r < 4; ++r) {
          int grow = tM + wr * 64 + m * 16 + kg * 4 + r;
          int gcol = tN + wc * 64 + n * 16 + lr;
          size_t idx = (size_t)grow * N + gcol;
          float v = acc[m][n][r];
          if (EPI == 1) {
            float g = mo[(size_t)(grow >> 10) * 6912 + goff + gcol];
            Cf[idx] = res[idx] + g * (v + bias[gcol]);
          } else {
            float z = v + bias[gcol];
            Cb[idx] = f2bf(0.5f * z * (1.f + erff(z * 0.70710678118f)));
          }
        }
  }
}

// ------- fc2 split-K reduce: out = x1 + g_mlp*(p0+p1+bias) -------
__global__ __launch_bounds__(256) void k_fc2red(const float* __restrict__ p,
                                                const float* __restrict__ x1,
                                                const float* __restrict__ bias,
                                                const float* __restrict__ mo,
                                                float* __restrict__ out) {
  size_t i = ((size_t)blockIdx.x * 256 + threadIdx.x) * 4;  // over 8192*1152
  int row = (int)(i / 1152);
  int col = (int)(i - (size_t)row * 1152);
  int b = row >> 10;
  float4 a0 = *(const float4*)(p + i);
  float4 a1 = *(const float4*)(p + 9437184ull + i);
  float4 r = *(const float4*)(x1 + i);
  const float* gp = mo + (size_t)b * 6912 + 5760 + col;
  const float* bp = bias + col;
  float4 o;
  o.x = r.x + gp[0] * (a0.x + a1.x + bp[0]);
  o.y = r.y + gp[1] * (a0.y + a1.y + bp[1]);
  o.z = r.z + gp[2] * (a0.z + a1.z + bp[2]);
  o.w = r.w + gp[3] * (a0.w + a1.w + bp[3]);
  *(float4*)(out + i) = o;
}

// ------- flash attention, swapped-QK^T structure -------
__global__ __launch_bounds__(256) void k_attn(const u16* __restrict__ QKV, const u16* __restrict__ Vt,
                                              u16* __restrict__ O) {
  const int tid = threadIdx.x;
  const int w = tid >> 6, lane = tid & 63;
  const int lr = lane & 15, kg = lane >> 4;
  int bx = blockIdx.x;
  bx = (bx & 7) * 256 + (bx >> 3);  // XCD-chunk swizzle: one batch per XCD
  const int qt = bx & 15, h = (bx >> 4) & 15, b = bx >> 8;

  __shared__ u16 lQ[64][104];
  __shared__ u16 lK[64][104];
  __shared__ u16 lVt[80][72];
  __shared__ u16 lPt[4][16][72];

  const size_t qkbase = (size_t)b * 1024 * 3456 + (size_t)h * 72;
  const u16* Qg = QKV + qkbase;
  const u16* Kg = QKV + qkbase + 1152;
  const u16* Vg = Vt + ((size_t)(b * 16 + h) * 72) * 1024;

  const uint4 z4 = make_uint4(0, 0, 0, 0);
  for (int L = tid; L < 192; L += 256) {
    int r = L / 3, s = L - (L / 3) * 3;
    *(uint4*)&lQ[r][72 + s * 8] = z4;
    *(uint4*)&lK[r][72 + s * 8] = z4;
  }
  for (int L = tid; L < 72; L += 256) {
    int r = L / 9, s = L - (L / 9) * 9;
    *(uint4*)&lVt[72 + r][s * 8] = z4;
  }
  {
    int L = tid; int r = L / 9, s = L - r * 9;
    *(uint4*)&lQ[r][s * 8] = *(const uint4*)(Qg + (size_t)(qt * 64 + r) * 3456 + s * 8);
    L = tid + 256; r = L / 9; s = L - r * 9;
    *(uint4*)&lQ[r][s * 8] = *(const uint4*)(Qg + (size_t)(qt * 64 + r) * 3456 + s * 8);
    if (tid < 64) {
      L = tid + 512; r = L / 9; s = L - r * 9;
      *(uint4*)&lQ[r][s * 8] = *(const uint4*)(Qg + (size_t)(qt * 64 + r) * 3456 + s * 8);
    }
  }
  __syncthreads();

  bf16x8 bq[3];
  #pragma unroll
  for (int ks = 0; ks < 3; ++ks) bq[ks] = *(const bf16x8*)&lQ[w * 16 + lr][ks * 32 + kg * 8];

  const float scale = 0.11785113019775793f;  // 1/sqrt(72)
  float mrun = -1e30f, lrun = 0.f;
  f32x4 oacc[5];
  #pragma unroll
  for (int nd = 0; nd < 5; ++nd) oacc[nd] = f32x4{0.f, 0.f, 0.f, 0.f};

  for (int kt = 0; kt < 16; ++kt) {
    __syncthreads();
    {
      int L = tid; int r = L / 9, s = L - (L / 9) * 9;
      *(uint4*)&lK[r][s * 8] = *(const uint4*)(Kg + (size_t)(kt * 64 + r) * 3456 + s * 8);
      int d = tid >> 3, sg = tid & 7;
      *(uint4*)&lVt[d][sg * 8] = *(const uint4*)(Vg + (size_t)d * 1024 + kt * 64 + sg * 8);
      L = tid + 256; r = L / 9; s = L - r * 9;
      *(uint4*)&lK[r][s * 8] = *(const uint4*)(Kg + (size_t)(kt * 64 + r) * 3456 + s * 8);
      d = (tid + 256) >> 3; sg = tid & 7;
      *(uint4*)&lVt[d][sg * 8] = *(const uint4*)(Vg + (size_t)d * 1024 + kt * 64 + sg * 8);
      if (tid < 64) {
        L = tid + 512; r = L / 9; s = L - r * 9;
        *(uint4*)&lK[r][s * 8] = *(const uint4*)(Kg + (size_t)(kt * 64 + r) * 3456 + s * 8);
        d = (tid + 512) >> 3;
        *(uint4*)&lVt[d][sg * 8] = *(const uint4*)(Vg + (size_t)d * 1024 + kt * 64 + sg * 8);
      }
    }
    __syncthreads();

    f32x4 sfr[4];
    __builtin_amdgcn_s_setprio(1);
    #pragma unroll
    for (int kb = 0; kb < 4; ++kb) {
      f32x4 sv = f32x4{0.f, 0.f, 0.f, 0.f};
      #pragma unroll
      for (int ks = 0; ks < 3; ++ks) {
        bf16x8 ak = *(const bf16x8*)&lK[kb * 16 + lr][ks * 32 + kg * 8];
        sv = MFMA16(ak, bq[ks], sv);
      }
      sfr[kb] = sv;
    }
    __builtin_amdgcn_s_setprio(0);

    float mx = sfr[0][0];
    #pragma unroll
    for (int kb = 0; kb < 4; ++kb)
      #pragma unroll
      for (int r = 0; r < 4; ++r) mx = fmaxf(mx, sfr[kb][r]);
    mx = fmaxf(mx, __shfl_xor(mx, 16));
    mx = fmaxf(mx, __shfl_xor(mx, 32));
    mx *= scale;
    float mn = fmaxf(mrun, mx);
    float al = __expf(mrun - mn);
    mrun = mn;
    float sum = 0.f;
    #pragma unroll
    for (int kb = 0; kb < 4; ++kb) {
      #pragma unroll
      for (int rp = 0; rp < 2; ++rp) {
        float p0 = __expf(__fmaf_rn(sfr[kb][2 * rp], scale, -mn));
        float p1 = __expf(__fmaf_rn(sfr[kb][2 * rp + 1], scale, -mn));
        sum += p0 + p1;
        u32 pk = (u32)f2bf(p0) | ((u32)f2bf(p1) << 16);
        *(u32*)&lPt[w][lr][kb * 16 + kg * 4 + rp * 2] = pk;
      }
    }
    sum += __shfl_xor(sum, 16);
    sum += __shfl_xor(sum, 32);
    lrun = lrun * al + sum;
    #pragma unroll
    for (int nd = 0; nd < 5; ++nd)
      #pragma unroll
      for (int r = 0; r < 4; ++r) oacc[nd][r] *= al;

    __builtin_amdgcn_s_setprio(1);
    #pragma unroll
    for (int s = 0; s < 2; ++s) {
      bf16x8 bp = *(const bf16x8*)&lPt[w][lr][s * 32 + kg * 8];
      #pragma unroll
      for (int nd = 0; nd < 5; ++nd) {
        bf16x8 av = *(const bf16x8*)&lVt[nd * 16 + lr][s * 32 + kg * 8];
        oacc[nd] = MFMA16(av, bp, oacc[nd]);
      }
    }
    __builtin_amdgcn_s_setprio(0);
  }

  float inv = 1.f / lrun;
  size_t orow = ((size_t)b * 1024 + qt * 64 + w * 16 + lr) * 1152 + h * 72;
  #pragma unroll
  for (int nd = 0; nd < 5; ++nd) {
    int d0 = nd * 16 + kg * 4;
    if (d0 < 72) {
      ushort4 u;
      u.x = f2bf(oacc[nd][0] * inv);
      u.y = f2bf(oacc[nd][1] * inv);
      u.z = f2bf(oacc[nd][2] * inv);
      u.w = f2bf(oacc[nd][3] * inv);
      *(ushort4*)&O[orow + d0] = u;
    }
  }
}

extern "C" void kernel_launch(void* const* d_in, const int* in_sizes, int n_in,
                              void* d_out, int out_size, void* d_ws, size_t ws_size,
                              hipStream_t stream) {
  const float* x     = (const float*)d_in[0];
  const float* c     = (const float*)d_in[1];
  const float* ln1_w = (const float*)d_in[2];
  const float* ln1_b = (const float*)d_in[3];
  const float* wq    = (const float*)d_in[4];
  const float* wk    = (const float*)d_in[5];
  const float* wv    = (const float*)d_in[6];
  const float* wo    = (const float*)d_in[7];
  const float* wo_b  = (const float*)d_in[8];
  const float* ln2_w = (const float*)d_in[9];
  const float* ln2_b = (const float*)d_in[10];
  const float* fc1_w = (const float*)d_in[11];
  const float* fc1_b = (const float*)d_in[12];
  const float* fc2_w = (const float*)d_in[13];
  const float* fc2_b = (const float*)d_in[14];
  const float* ada_w = (const float*)d_in[15];
  const float* ada_b = (const float*)d_in[16];
  float* out = (float*)d_out;

  char* base = (char*)d_ws;
  size_t off = 0;
  auto alloc = [&](size_t nbytes) -> void* {
    void* p = base + off;
    off += (nbytes + 255) & ~(size_t)255;
    return p;
  };
  const size_t MD = 8192ull * 1152;
  float* silu_c = (float*)alloc(9216 * 4);
  float* partial = (float*)alloc(64ull * 6912 * 4);
  float* modb   = (float*)alloc(55296 * 4);
  u16* qkvT = (u16*)alloc(3456ull * 1152 * 2);
  u16* woT  = (u16*)alloc(1152ull * 1152 * 2);
  u16* fc1T = (u16*)alloc(4608ull * 1152 * 2);
  u16* fc2T = (u16*)alloc(1152ull * 4608 * 2);
  u16* hbuf = (u16*)alloc(MD * 2);               // h -> attnO -> h2
  float* x1 = (float*)alloc(MD * 4);
  u16* vtb  = (u16*)alloc(128ull * 72 * 1024 * 2);  // V transposed [b,h,d,s]
  float* fc2p = (float*)alloc(2ull * MD * 4);    // fc2 split-K partials
  u16* big  = (u16*)alloc(8192ull * 4608 * 2);   // qkv (Q,K used) then m1
  u16* qkv = big;
  u16* m1 = big;

  k_silu<<<36, 256, 0, stream>>>(c, silu_c, 9216);
  k_modproj1<<<dim3(27, 8), 256, 0, stream>>>(silu_c, ada_w, partial);
  k_modproj2<<<27, 256, 0, stream>>>(partial, ada_b, modb);
  k_tcvt<<<dim3(36, 36), 256, 0, stream>>>(wq, qkvT, 1152, 1152);
  k_tcvt<<<dim3(36, 36), 256, 0, stream>>>(wk, qkvT + 1152ull * 1152, 1152, 1152);
  k_tcvt<<<dim3(36, 36), 256, 0, stream>>>(wv, qkvT + 2304ull * 1152, 1152, 1152);
  k_tcvt<<<dim3(36, 36), 256, 0, stream>>>(wo, woT, 1152, 1152);
  k_tcvt<<<dim3(144, 36), 256, 0, stream>>>(fc1_w, fc1T, 1152, 4608);
  k_tcvt<<<dim3(36, 144), 256, 0, stream>>>(fc2_w, fc2T, 4608, 1152);

  // h = modulate(LN(x), sh_msa, sc_msa)
  k_lnmod<<<8192, 256, 0, stream>>>(x, ln1_w, ln1_b, modb, 0, 1152, hbuf);
  // qkv: Q,K rows into qkv buffer, V transposed into vtb
  k_gemm<3><<<dim3(27, 64), 256, 0, stream>>>(hbuf, qkvT, 1152, 1152, qkv, nullptr, nullptr, nullptr, nullptr, 0, vtb);
  // attention -> O (reuse hbuf)
  k_attn<<<2048, 256, 0, stream>>>(qkv, vtb, hbuf);
  // x1 = x + g_msa*(O@wo + wo_b)
  k_gemm<1><<<dim3(9, 64), 256, 0, stream>>>(hbuf, woT, 1152, 1152, nullptr, x1, wo_b, x, modb, 2304, nullptr);
  // h2 = modulate(LN(x1), sh_mlp, sc_mlp)
  k_lnmod<<<8192, 256, 0, stream>>>(x1, ln2_w, ln2_b, modb, 3456, 4608, hbuf);
  // m1 = gelu(h2@fc1 + fc1_b)
  k_gemm<2><<<dim3(36, 64), 256, 0, stream>>>(hbuf, fc1T, 1152, 1152, m1, nullptr, fc1_b, nullptr, nullptr, 0, nullptr);
  // fc2 split-K x2: partials then fused reduce
  k_gemm<4><<<dim3(9, 64, 2), 256, 0, stream>>>(m1, fc2T, 4608, 2304, nullptr, fc2p, nullptr, nullptr, nullptr, 0, nullptr);
  k_fc2red<<<9216, 256, 0, stream>>>(fc2p, x1, fc2_b, modb, out);
}

// Round 5
// 603.196 us; speedup vs baseline: 1.6017x; 1.1039x over previous
//
#include <hip/hip_runtime.h>
#include <hip/hip_bf16.h>

// DiT block: B=8, S=1024, D=1152, H=16, HD=72, HID=4608
// GEMMs: bf16 MFMA 16x16x32, f32 accum, 128x128 tile, BK=32, global_load_lds,
// statically-unrolled 2-phase double-buffered pipeline (1 barrier/K-step).
// fc1 epilogue: fast sigmoid-form gelu. fc2 split-K x2 + fused reduce.
// Attention: swapped QK^T, pre-transposed V, in-lane softmax.

typedef unsigned short u16;
typedef unsigned int u32;
typedef __attribute__((ext_vector_type(8))) short bf16x8;
typedef __attribute__((ext_vector_type(4))) float f32x4;

#define MFMA16(a, b, c) __builtin_amdgcn_mfma_f32_16x16x32_bf16((a), (b), (c), 0, 0, 0)

__device__ __forceinline__ u16 f2bf(float f) {
  __hip_bfloat16 h = __float2bfloat16(f);
  return __builtin_bit_cast(u16, h);
}

__device__ __forceinline__ void gload16(const u16* g, u16* l) {
  __builtin_amdgcn_global_load_lds(
      (const __attribute__((address_space(1))) unsigned int*)(const void*)g,
      (__attribute__((address_space(3))) unsigned int*)(void*)l, 16, 0, 0);
}

// ---------------- silu(c) ----------------
__global__ void k_silu(const float* __restrict__ c, float* __restrict__ o, int n) {
  int i = blockIdx.x * 256 + threadIdx.x;
  if (i < n) { float v = c[i]; o[i] = v / (1.f + __expf(-v)); }
}

// ------- mod projection, split-K stage 1 -------
__global__ __launch_bounds__(256) void k_modproj1(const float* __restrict__ sc,
                                                  const float* __restrict__ aw,
                                                  float* __restrict__ partial) {
  __shared__ float lc[8][144];
  int kc = blockIdx.y;
  for (int i = threadIdx.x; i < 1152; i += 256) {
    int b = i / 144, k = i % 144;
    lc[b][k] = sc[b * 1152 + kc * 144 + k];
  }
  __syncthreads();
  int j = blockIdx.x * 256 + threadIdx.x;
  float acc[8] = {0, 0, 0, 0, 0, 0, 0, 0};
  for (int k = 0; k < 144; ++k) {
    float w = aw[(size_t)(kc * 144 + k) * 6912 + j];
    #pragma unroll
    for (int b = 0; b < 8; ++b) acc[b] += lc[b][k] * w;
  }
  #pragma unroll
  for (int b = 0; b < 8; ++b) partial[((size_t)kc * 8 + b) * 6912 + j] = acc[b];
}

// ------- mod projection stage 2 -------
__global__ __launch_bounds__(256) void k_modproj2(const float* __restrict__ partial,
                                                  const float* __restrict__ ab,
                                                  float* __restrict__ mo) {
  int j = blockIdx.x * 256 + threadIdx.x;
  float bias = ab[j];
  #pragma unroll
  for (int b = 0; b < 8; ++b) {
    float s = 0.f;
    #pragma unroll
    for (int kc = 0; kc < 8; ++kc) s += partial[((size_t)kc * 8 + b) * 6912 + j];
    mo[(size_t)b * 6912 + j] = s + bias;
  }
}

// ------- transpose-convert: in[K][N] f32 -> out[N][K] bf16 -------
__global__ __launch_bounds__(256) void k_tcvt(const float* __restrict__ in, u16* __restrict__ out,
                                              int K, int N) {
  __shared__ float t[32][33];
  int tx = threadIdx.x & 31, ty = threadIdx.x >> 5;
  size_t bx = (size_t)blockIdx.x * 32, by = (size_t)blockIdx.y * 32;
  #pragma unroll
  for (int i = 0; i < 4; ++i) t[ty + 8 * i][tx] = in[(by + ty + 8 * i) * N + bx + tx];
  __syncthreads();
  #pragma unroll
  for (int i = 0; i < 4; ++i) out[(bx + ty + 8 * i) * K + by + tx] = f2bf(t[tx][ty + 8 * i]);
}

// ------- fused LayerNorm + modulate -> bf16 row -------
__global__ __launch_bounds__(256) void k_lnmod(const float* __restrict__ xin,
                                               const float* __restrict__ w,
                                               const float* __restrict__ bs,
                                               const float* __restrict__ mo,
                                               int sh_off, int sc_off, u16* __restrict__ o) {
  int row = blockIdx.x;
  int b = row >> 10;
  int tid = threadIdx.x;
  const float4* x4 = (const float4*)(xin + (size_t)row * 1152);
  float4 v0 = x4[tid];
  float4 v1 = make_float4(0.f, 0.f, 0.f, 0.f);
  if (tid < 32) v1 = x4[256 + tid];
  float s = v0.x + v0.y + v0.z + v0.w + v1.x + v1.y + v1.z + v1.w;
  float sq = v0.x * v0.x + v0.y * v0.y + v0.z * v0.z + v0.w * v0.w +
             v1.x * v1.x + v1.y * v1.y + v1.z * v1.z + v1.w * v1.w;
  #pragma unroll
  for (int d = 32; d > 0; d >>= 1) { s += __shfl_down(s, d); sq += __shfl_down(sq, d); }
  __shared__ float ps[4], pq[4];
  int wid = tid >> 6, lane = tid & 63;
  if (lane == 0) { ps[wid] = s; pq[wid] = sq; }
  __syncthreads();
  float S = ps[0] + ps[1] + ps[2] + ps[3];
  float SQ = pq[0] + pq[1] + pq[2] + pq[3];
  float mean = S * (1.f / 1152.f);
  float var = SQ * (1.f / 1152.f) - mean * mean;
  float rs = rsqrtf(var + 1e-5f);
  const float* shp = mo + (size_t)b * 6912 + sh_off;
  const float* scp = mo + (size_t)b * 6912 + sc_off;
  u16* orow = o + (size_t)row * 1152;
  {
    int col = 4 * tid;
    ushort4 u; float y;
    y = (v0.x - mean) * rs * w[col + 0] + bs[col + 0]; u.x = f2bf(y * (1.f + scp[col + 0]) + shp[col + 0]);
    y = (v0.y - mean) * rs * w[col + 1] + bs[col + 1]; u.y = f2bf(y * (1.f + scp[col + 1]) + shp[col + 1]);
    y = (v0.z - mean) * rs * w[col + 2] + bs[col + 2]; u.z = f2bf(y * (1.f + scp[col + 2]) + shp[col + 2]);
    y = (v0.w - mean) * rs * w[col + 3] + bs[col + 3]; u.w = f2bf(y * (1.f + scp[col + 3]) + shp[col + 3]);
    *(ushort4*)&orow[col] = u;
  }
  if (tid < 32) {
    int col = 1024 + 4 * tid;
    ushort4 u; float y;
    y = (v1.x - mean) * rs * w[col + 0] + bs[col + 0]; u.x = f2bf(y * (1.f + scp[col + 0]) + shp[col + 0]);
    y = (v1.y - mean) * rs * w[col + 1] + bs[col + 1]; u.y = f2bf(y * (1.f + scp[col + 1]) + shp[col + 1]);
    y = (v1.z - mean) * rs * w[col + 2] + bs[col + 2]; u.z = f2bf(y * (1.f + scp[col + 2]) + shp[col + 2]);
    y = (v1.w - mean) * rs * w[col + 3] + bs[col + 3]; u.w = f2bf(y * (1.f + scp[col + 3]) + shp[col + 3]);
    *(ushort4*)&orow[col] = u;
  }
}

// ------- bf16 MFMA GEMM, statically-unrolled 2-phase double-buffer -------
// C[M,N] = A[M,Kst](cols koff..koff+klen) @ Bt[N,Kst]^T ; klen/32 must be EVEN.
// EPI 1: Cf = res + mod*(acc+bias); EPI 2: Cb = bf16(gelu_fast(acc+bias));
// EPI 3: QKV (Q,K normal; V transposed to vt[b,h,d,s]); EPI 4: raw f32 partial (split-K)
template <int EPI>
__global__ __launch_bounds__(256) void k_gemm(const u16* __restrict__ A, const u16* __restrict__ Bt,
                                              int Kst, int klen, u16* __restrict__ Cb,
                                              float* __restrict__ Cf,
                                              const float* __restrict__ bias,
                                              const float* __restrict__ res,
                                              const float* __restrict__ mo, int goff,
                                              u16* __restrict__ vt) {
  const int tid = threadIdx.x;
  const int w = tid >> 6, lane = tid & 63;
  const int wr = w >> 1, wc = w & 1;
  const int lr = lane & 15, kg = lane >> 4;

  const int nwg = gridDim.x * gridDim.y;
  const int id = blockIdx.y * gridDim.x + blockIdx.x;
  const int swz = (id & 7) * (nwg >> 3) + (id >> 3);
  const int tM = (swz / gridDim.x) * 128, tN = (swz % gridDim.x) * 128;
  const int N = gridDim.x * 128;
  const int koff = blockIdx.z * klen;

  __shared__ u16 lA[2][128 * 32];
  __shared__ u16 lB[2][128 * 32];
  f32x4 acc[4][4];
  #pragma unroll
  for (int m = 0; m < 4; ++m)
    #pragma unroll
    for (int n = 0; n < 4; ++n) acc[m][n] = f32x4{0.f, 0.f, 0.f, 0.f};

  const int lrow = lane >> 2, lseg = lane & 3;
  const u16* gA = A + (size_t)(tM + w * 32 + lrow) * Kst + lseg * 8 + koff;
  const u16* gB = Bt + (size_t)(tN + w * 32 + lrow) * Kst + lseg * 8 + koff;
  const size_t rstep = (size_t)16 * Kst;
  const int wo0 = (w * 32) * 32, wo1 = (w * 32 + 16) * 32;
  const int aoff = (wr * 64 + lr) * 32 + kg * 8;
  const int boff = (wc * 64 + lr) * 32 + kg * 8;

#define STAGE(buf, ks)                        \
  do {                                        \
    gload16(gA + (ks), lA[buf] + wo0);        \
    gload16(gA + rstep + (ks), lA[buf] + wo1);\
    gload16(gB + (ks), lB[buf] + wo0);        \
    gload16(gB + rstep + (ks), lB[buf] + wo1);\
  } while (0)

#define COMPUTE(buf)                                                                  \
  do {                                                                                \
    bf16x8 af[4], bfr[4];                                                             \
    _Pragma("unroll")                                                                 \
    for (int m = 0; m < 4; ++m) af[m] = *(const bf16x8*)&lA[buf][aoff + m * 16 * 32]; \
    _Pragma("unroll")                                                                 \
    for (int n = 0; n < 4; ++n) bfr[n] = *(const bf16x8*)&lB[buf][boff + n * 16 * 32];\
    _Pragma("unroll")                                                                 \
    for (int m = 0; m < 4; ++m)                                                       \
      _Pragma("unroll")                                                               \
      for (int n = 0; n < 4; ++n) acc[m][n] = MFMA16(af[m], bfr[n], acc[m][n]);       \
  } while (0)

  // pipeline, nt even: buffer indices static everywhere
  const int nt = klen >> 5;
  STAGE(0, 0);
  __syncthreads();
  int t = 1;
  for (; t + 1 < nt; t += 2) {
    STAGE(1, t * 32);
    COMPUTE(0);
    __syncthreads();
    STAGE(0, t * 32 + 32);
    COMPUTE(1);
    __syncthreads();
  }
  STAGE(1, t * 32);
  COMPUTE(0);
  __syncthreads();
  COMPUTE(1);
#undef STAGE
#undef COMPUTE

  // epilogue: D row=(lane>>4)*4+reg, col=lane&15
  if (EPI == 3) {
    #pragma unroll
    for (int m = 0; m < 4; ++m)
      #pragma unroll
      for (int n = 0; n < 4; ++n) {
        int gcol = tN + wc * 64 + n * 16 + lr;
        int s0 = tM + wr * 64 + m * 16 + kg * 4;
        if (tN < 2304) {
          #pragma unroll
          for (int r = 0; r < 4; ++r) Cb[(size_t)(s0 + r) * N + gcol] = f2bf(acc[m][n][r]);
        } else {
          int qq = gcol - 2304;
          int hh = qq / 72;
          int d = qq - hh * 72;
          int bb = s0 >> 10, sl = s0 & 1023;
          ushort4 u;
          u.x = f2bf(acc[m][n][0]); u.y = f2bf(acc[m][n][1]);
          u.z = f2bf(acc[m][n][2]); u.w = f2bf(acc[m][n][3]);
          *(ushort4*)&vt[(((size_t)bb * 16 + hh) * 72 + d) * 1024 + sl] = u;
        }
      }
  } else if (EPI == 4) {
    float* Po = Cf + (size_t)blockIdx.z * ((size_t)gridDim.y * 128) * N;
    #pragma unroll
    for (int m = 0; m < 4; ++m)
      #pragma unroll
      for (int n = 0; n < 4; ++n)
        #pragma unroll
        for (int r = 0; r < 4; ++r) {
          int grow = tM + wr * 64 + m * 16 + kg * 4 + r;
          int gcol = tN + wc * 64 + n * 16 + lr;
          Po[(size_t)grow * N + gcol] = acc[m][n][r];
        }
  } else {
    #pragma unroll
    for (int m = 0; m < 4; ++m)
      #pragma unroll
      for (int n = 0; n < 4; ++n)
        #pragma unroll
        for (int r = 0; r < 4; ++r) {
          int grow = tM + wr * 64 + m * 16 + kg * 4 + r;
          int gcol = tN + wc * 64 + n * 16 + lr;
          size_t idx = (size_t)grow * N + gcol;
          float v = acc[m][n][r];
          if (EPI == 1) {
            float g = mo[(size_t)(grow >> 10) * 6912 + goff + gcol];
            Cf[idx] = res[idx] + g * (v + bias[gcol]);
          } else {
            // fast gelu: z * sigmoid(1.5957691216 z + 0.0713548162 z^3)
            float z = v + bias[gcol];
            float z2 = z * z;
            float u = z * __fmaf_rn(z2, -0.0713548162f, -1.5957691216f);
            float e = __expf(u);
            float gel = z * __builtin_amdgcn_rcpf(1.f + e);
            Cb[idx] = f2bf(gel);
          }
        }
  }
}

// ------- fc2 split-K reduce: out = x1 + g_mlp*(p0+p1+bias) -------
__global__ __launch_bounds__(256) void k_fc2red(const float* __restrict__ p,
                                                const float* __restrict__ x1,
                                                const float* __restrict__ bias,
                                                const float* __restrict__ mo,
                                                float* __restrict__ out) {
  size_t i = ((size_t)blockIdx.x * 256 + threadIdx.x) * 4;  // over 8192*1152
  int row = (int)(i / 1152);
  int col = (int)(i - (size_t)row * 1152);
  int b = row >> 10;
  float4 a0 = *(const float4*)(p + i);
  float4 a1 = *(const float4*)(p + 9437184ull + i);
  float4 r = *(const float4*)(x1 + i);
  const float* gp = mo + (size_t)b * 6912 + 5760 + col;
  const float* bp = bias + col;
  float4 o;
  o.x = r.x + gp[0] * (a0.x + a1.x + bp[0]);
  o.y = r.y + gp[1] * (a0.y + a1.y + bp[1]);
  o.z = r.z + gp[2] * (a0.z + a1.z + bp[2]);
  o.w = r.w + gp[3] * (a0.w + a1.w + bp[3]);
  *(float4*)(out + i) = o;
}

// ------- flash attention, swapped-QK^T structure -------
__global__ __launch_bounds__(256) void k_attn(const u16* __restrict__ QKV, const u16* __restrict__ Vt,
                                              u16* __restrict__ O) {
  const int tid = threadIdx.x;
  const int w = tid >> 6, lane = tid & 63;
  const int lr = lane & 15, kg = lane >> 4;
  int bx = blockIdx.x;
  bx = (bx & 7) * 256 + (bx >> 3);  // XCD-chunk swizzle: one batch per XCD
  const int qt = bx & 15, h = (bx >> 4) & 15, b = bx >> 8;

  __shared__ u16 lQ[64][104];
  __shared__ u16 lK[64][104];
  __shared__ u16 lVt[80][72];
  __shared__ u16 lPt[4][16][72];

  const size_t qkbase = (size_t)b * 1024 * 3456 + (size_t)h * 72;
  const u16* Qg = QKV + qkbase;
  const u16* Kg = QKV + qkbase + 1152;
  const u16* Vg = Vt + ((size_t)(b * 16 + h) * 72) * 1024;

  const uint4 z4 = make_uint4(0, 0, 0, 0);
  for (int L = tid; L < 192; L += 256) {
    int r = L / 3, s = L - (L / 3) * 3;
    *(uint4*)&lQ[r][72 + s * 8] = z4;
    *(uint4*)&lK[r][72 + s * 8] = z4;
  }
  for (int L = tid; L < 72; L += 256) {
    int r = L / 9, s = L - (L / 9) * 9;
    *(uint4*)&lVt[72 + r][s * 8] = z4;
  }
  {
    int L = tid; int r = L / 9, s = L - r * 9;
    *(uint4*)&lQ[r][s * 8] = *(const uint4*)(Qg + (size_t)(qt * 64 + r) * 3456 + s * 8);
    L = tid + 256; r = L / 9; s = L - r * 9;
    *(uint4*)&lQ[r][s * 8] = *(const uint4*)(Qg + (size_t)(qt * 64 + r) * 3456 + s * 8);
    if (tid < 64) {
      L = tid + 512; r = L / 9; s = L - r * 9;
      *(uint4*)&lQ[r][s * 8] = *(const uint4*)(Qg + (size_t)(qt * 64 + r) * 3456 + s * 8);
    }
  }
  __syncthreads();

  bf16x8 bq[3];
  #pragma unroll
  for (int ks = 0; ks < 3; ++ks) bq[ks] = *(const bf16x8*)&lQ[w * 16 + lr][ks * 32 + kg * 8];

  const float scale = 0.11785113019775793f;  // 1/sqrt(72)
  float mrun = -1e30f, lrun = 0.f;
  f32x4 oacc[5];
  #pragma unroll
  for (int nd = 0; nd < 5; ++nd) oacc[nd] = f32x4{0.f, 0.f, 0.f, 0.f};

  for (int kt = 0; kt < 16; ++kt) {
    __syncthreads();
    {
      int L = tid; int r = L / 9, s = L - (L / 9) * 9;
      *(uint4*)&lK[r][s * 8] = *(const uint4*)(Kg + (size_t)(kt * 64 + r) * 3456 + s * 8);
      int d = tid >> 3, sg = tid & 7;
      *(uint4*)&lVt[d][sg * 8] = *(const uint4*)(Vg + (size_t)d * 1024 + kt * 64 + sg * 8);
      L = tid + 256; r = L / 9; s = L - r * 9;
      *(uint4*)&lK[r][s * 8] = *(const uint4*)(Kg + (size_t)(kt * 64 + r) * 3456 + s * 8);
      d = (tid + 256) >> 3; sg = tid & 7;
      *(uint4*)&lVt[d][sg * 8] = *(const uint4*)(Vg + (size_t)d * 1024 + kt * 64 + sg * 8);
      if (tid < 64) {
        L = tid + 512; r = L / 9; s = L - r * 9;
        *(uint4*)&lK[r][s * 8] = *(const uint4*)(Kg + (size_t)(kt * 64 + r) * 3456 + s * 8);
        d = (tid + 512) >> 3;
        *(uint4*)&lVt[d][sg * 8] = *(const uint4*)(Vg + (size_t)d * 1024 + kt * 64 + sg * 8);
      }
    }
    __syncthreads();

    f32x4 sfr[4];
    __builtin_amdgcn_s_setprio(1);
    #pragma unroll
    for (int kb = 0; kb < 4; ++kb) {
      f32x4 sv = f32x4{0.f, 0.f, 0.f, 0.f};
      #pragma unroll
      for (int ks = 0; ks < 3; ++ks) {
        bf16x8 ak = *(const bf16x8*)&lK[kb * 16 + lr][ks * 32 + kg * 8];
        sv = MFMA16(ak, bq[ks], sv);
      }
      sfr[kb] = sv;
    }
    __builtin_amdgcn_s_setprio(0);

    float mx = sfr[0][0];
    #pragma unroll
    for (int kb = 0; kb < 4; ++kb)
      #pragma unroll
      for (int r = 0; r < 4; ++r) mx = fmaxf(mx, sfr[kb][r]);
    mx = fmaxf(mx, __shfl_xor(mx, 16));
    mx = fmaxf(mx, __shfl_xor(mx, 32));
    mx *= scale;
    float mn = fmaxf(mrun, mx);
    float al = __expf(mrun - mn);
    mrun = mn;
    float sum = 0.f;
    #pragma unroll
    for (int kb = 0; kb < 4; ++kb) {
      #pragma unroll
      for (int rp = 0; rp < 2; ++rp) {
        float p0 = __expf(__fmaf_rn(sfr[kb][2 * rp], scale, -mn));
        float p1 = __expf(__fmaf_rn(sfr[kb][2 * rp + 1], scale, -mn));
        sum += p0 + p1;
        u32 pk = (u32)f2bf(p0) | ((u32)f2bf(p1) << 16);
        *(u32*)&lPt[w][lr][kb * 16 + kg * 4 + rp * 2] = pk;
      }
    }
    sum += __shfl_xor(sum, 16);
    sum += __shfl_xor(sum, 32);
    lrun = lrun * al + sum;
    #pragma unroll
    for (int nd = 0; nd < 5; ++nd)
      #pragma unroll
      for (int r = 0; r < 4; ++r) oacc[nd][r] *= al;

    __builtin_amdgcn_s_setprio(1);
    #pragma unroll
    for (int s = 0; s < 2; ++s) {
      bf16x8 bp = *(const bf16x8*)&lPt[w][lr][s * 32 + kg * 8];
      #pragma unroll
      for (int nd = 0; nd < 5; ++nd) {
        bf16x8 av = *(const bf16x8*)&lVt[nd * 16 + lr][s * 32 + kg * 8];
        oacc[nd] = MFMA16(av, bp, oacc[nd]);
      }
    }
    __builtin_amdgcn_s_setprio(0);
  }

  float inv = 1.f / lrun;
  size_t orow = ((size_t)b * 1024 + qt * 64 + w * 16 + lr) * 1152 + h * 72;
  #pragma unroll
  for (int nd = 0; nd < 5; ++nd) {
    int d0 = nd * 16 + kg * 4;
    if (d0 < 72) {
      ushort4 u;
      u.x = f2bf(oacc[nd][0] * inv);
      u.y = f2bf(oacc[nd][1] * inv);
      u.z = f2bf(oacc[nd][2] * inv);
      u.w = f2bf(oacc[nd][3] * inv);
      *(ushort4*)&O[orow + d0] = u;
    }
  }
}

extern "C" void kernel_launch(void* const* d_in, const int* in_sizes, int n_in,
                              void* d_out, int out_size, void* d_ws, size_t ws_size,
                              hipStream_t stream) {
  const float* x     = (const float*)d_in[0];
  const float* c     = (const float*)d_in[1];
  const float* ln1_w = (const float*)d_in[2];
  const float* ln1_b = (const float*)d_in[3];
  const float* wq    = (const float*)d_in[4];
  const float* wk    = (const float*)d_in[5];
  const float* wv    = (const float*)d_in[6];
  const float* wo    = (const float*)d_in[7];
  const float* wo_b  = (const float*)d_in[8];
  const float* ln2_w = (const float*)d_in[9];
  const float* ln2_b = (const float*)d_in[10];
  const float* fc1_w = (const float*)d_in[11];
  const float* fc1_b = (const float*)d_in[12];
  const float* fc2_w = (const float*)d_in[13];
  const float* fc2_b = (const float*)d_in[14];
  const float* ada_w = (const float*)d_in[15];
  const float* ada_b = (const float*)d_in[16];
  float* out = (float*)d_out;

  char* base = (char*)d_ws;
  size_t off = 0;
  auto alloc = [&](size_t nbytes) -> void* {
    void* p = base + off;
    off += (nbytes + 255) & ~(size_t)255;
    return p;
  };
  const size_t MD = 8192ull * 1152;
  float* silu_c = (float*)alloc(9216 * 4);
  float* partial = (float*)alloc(64ull * 6912 * 4);
  float* modb   = (float*)alloc(55296 * 4);
  u16* qkvT = (u16*)alloc(3456ull * 1152 * 2);
  u16* woT  = (u16*)alloc(1152ull * 1152 * 2);
  u16* fc1T = (u16*)alloc(4608ull * 1152 * 2);
  u16* fc2T = (u16*)alloc(1152ull * 4608 * 2);
  u16* hbuf = (u16*)alloc(MD * 2);               // h -> attnO -> h2
  float* x1 = (float*)alloc(MD * 4);
  u16* vtb  = (u16*)alloc(128ull * 72 * 1024 * 2);  // V transposed [b,h,d,s]
  float* fc2p = (float*)alloc(2ull * MD * 4);    // fc2 split-K partials
  u16* big  = (u16*)alloc(8192ull * 4608 * 2);   // qkv (Q,K used) then m1
  u16* qkv = big;
  u16* m1 = big;

  k_silu<<<36, 256, 0, stream>>>(c, silu_c, 9216);
  k_modproj1<<<dim3(27, 8), 256, 0, stream>>>(silu_c, ada_w, partial);
  k_modproj2<<<27, 256, 0, stream>>>(partial, ada_b, modb);
  k_tcvt<<<dim3(36, 36), 256, 0, stream>>>(wq, qkvT, 1152, 1152);
  k_tcvt<<<dim3(36, 36), 256, 0, stream>>>(wk, qkvT + 1152ull * 1152, 1152, 1152);
  k_tcvt<<<dim3(36, 36), 256, 0, stream>>>(wv, qkvT + 2304ull * 1152, 1152, 1152);
  k_tcvt<<<dim3(36, 36), 256, 0, stream>>>(wo, woT, 1152, 1152);
  k_tcvt<<<dim3(144, 36), 256, 0, stream>>>(fc1_w, fc1T, 1152, 4608);
  k_tcvt<<<dim3(36, 144), 256, 0, stream>>>(fc2_w, fc2T, 4608, 1152);

  // h = modulate(LN(x), sh_msa, sc_msa)
  k_lnmod<<<8192, 256, 0, stream>>>(x, ln1_w, ln1_b, modb, 0, 1152, hbuf);
  // qkv: Q,K rows into qkv buffer, V transposed into vtb
  k_gemm<3><<<dim3(27, 64), 256, 0, stream>>>(hbuf, qkvT, 1152, 1152, qkv, nullptr, nullptr, nullptr, nullptr, 0, vtb);
  // attention -> O (reuse hbuf)
  k_attn<<<2048, 256, 0, stream>>>(qkv, vtb, hbuf);
  // x1 = x + g_msa*(O@wo + wo_b)
  k_gemm<1><<<dim3(9, 64), 256, 0, stream>>>(hbuf, woT, 1152, 1152, nullptr, x1, wo_b, x, modb, 2304, nullptr);
  // h2 = modulate(LN(x1), sh_mlp, sc_mlp)
  k_lnmod<<<8192, 256, 0, stream>>>(x1, ln2_w, ln2_b, modb, 3456, 4608, hbuf);
  // m1 = gelu(h2@fc1 + fc1_b)
  k_gemm<2><<<dim3(36, 64), 256, 0, stream>>>(hbuf, fc1T, 1152, 1152, m1, nullptr, fc1_b, nullptr, nullptr, 0, nullptr);
  // fc2 split-K x2: partials then fused reduce
  k_gemm<4><<<dim3(9, 64, 2), 256, 0, stream>>>(m1, fc2T, 4608, 2304, nullptr, fc2p, nullptr, nullptr, nullptr, 0, nullptr);
  k_fc2red<<<9216, 256, 0, stream>>>(fc2p, x1, fc2_b, modb, out);
}